// Round 2
// baseline (2312.277 us; speedup 1.0000x reference)
//
#include <hip/hip_runtime.h>
#include <stdint.h>

#define NN 100000
#define EE 1600000
#define IN_C 128
#define HID_C 256
#define OUT_C 64

typedef unsigned short bf16_t;
typedef unsigned int u32;

__device__ __forceinline__ float b2f(unsigned short u){
  unsigned int x = ((unsigned int)u) << 16;
  return __uint_as_float(x);
}
__device__ __forceinline__ unsigned short f2b(float f){
  unsigned int x = __float_as_uint(f);
  unsigned int r = x + 0x7FFFu + ((x >> 16) & 1u);   // RNE
  return (unsigned short)(r >> 16);
}
__device__ __forceinline__ float cvt(float v){ return v; }
__device__ __forceinline__ float cvt(bf16_t v){ return b2f(v); }
__device__ __forceinline__ void sto(float* p, float v){ *p = v; }
__device__ __forceinline__ void sto(bf16_t* p, float v){ *p = f2b(v); }

// ---------------- edge dtype detector ----------------
// int64 edge_index (values < 2^31): all odd 32-bit words of the first 1024
// entries are zero. int32: they are random node ids (nonzero w.h.p.).
__global__ void detect_edge_k(const int* __restrict__ ei, int* __restrict__ eflag){
  __shared__ int sm[256];
  int t = threadIdx.x;
  int o = 0;
  for (int i = t; i < 1024; i += 256) o |= ei[2*i + 1];
  sm[t] = o; __syncthreads();
  for (int s = 128; s > 0; s >>= 1){
    if (t < s) sm[t] |= sm[t + s];
    __syncthreads();
  }
  if (t == 0) *eflag = (sm[0] == 0) ? 1 : 0;   // 1 = int64 layout
}

// ---------------- CSR build ----------------

__global__ void count_deg_k(const int* __restrict__ ei, const int* __restrict__ eflag,
                            int* __restrict__ deg){
  int g = blockIdx.x * blockDim.x + threadIdx.x;
  if (g < EE){
    int i64 = *eflag;
    int d = i64 ? ei[2*(EE + g)] : ei[EE + g];
    atomicAdd(&deg[d], 1);
  }
}

__global__ void deginv_k(const int* __restrict__ deg, float* __restrict__ dinv){
  int g = blockIdx.x * blockDim.x + threadIdx.x;
  if (g < NN){ int d = deg[g]; dinv[g] = d > 0 ? 1.0f / (float)d : 0.0f; }
}

__global__ void scan1_k(const int* __restrict__ deg, int* __restrict__ rowptr,
                        int* __restrict__ bsums){
  __shared__ int sm[256];
  int t = threadIdx.x;
  int g = blockIdx.x * 256 + t;
  int v = (g < NN) ? deg[g] : 0;
  sm[t] = v; __syncthreads();
  for (int off = 1; off < 256; off <<= 1){
    int add = (t >= off) ? sm[t - off] : 0;
    __syncthreads();
    sm[t] += add;
    __syncthreads();
  }
  if (g < NN) rowptr[g + 1] = sm[t];
  if (t == 255) bsums[blockIdx.x] = sm[255];
}

__global__ void scan2_k(int* __restrict__ bsums, int nb){
  __shared__ int sm[512];
  int t = threadIdx.x;
  sm[t] = (t < nb) ? bsums[t] : 0; __syncthreads();
  for (int off = 1; off < 512; off <<= 1){
    int add = (t >= off) ? sm[t - off] : 0;
    __syncthreads();
    sm[t] += add;
    __syncthreads();
  }
  if (t < nb) bsums[t] = sm[t];
}

__global__ void scan3_k(int* __restrict__ rowptr, const int* __restrict__ bsums){
  int g = blockIdx.x * 256 + threadIdx.x;
  if (g < NN && blockIdx.x > 0) rowptr[g + 1] += bsums[blockIdx.x - 1];
  if (g == 0) rowptr[0] = 0;
}

__global__ void fill_k(const int* __restrict__ ei, const int* __restrict__ eflag,
                       const int* __restrict__ rowptr, int* __restrict__ fill,
                       int* __restrict__ csr){
  int g = blockIdx.x * blockDim.x + threadIdx.x;
  if (g < EE){
    int i64 = *eflag;
    int s = i64 ? ei[2*g]          : ei[g];
    int d = i64 ? ei[2*(EE + g)]   : ei[EE + g];
    int pos = rowptr[d] + atomicAdd(&fill[d], 1);
    csr[pos] = s;
  }
}

// ---------------- mean aggregation: one wave per node ----------------
// input rows of type T (f32 or internal bf16), output internal bf16

template<int C, typename T>
__global__ __launch_bounds__(256) void agg_mean_k(const T* __restrict__ h,
    const int* __restrict__ rowptr, const int* __restrict__ csr,
    const float* __restrict__ dinv, bf16_t* __restrict__ outm){
  constexpr int VEC = C / 64;                 // elements per lane: 2 or 4
  int wid  = (blockIdx.x * 256 + threadIdx.x) >> 6;
  int lane = threadIdx.x & 63;
  if (wid >= NN) return;
  int beg = rowptr[wid], end = rowptr[wid + 1];
  float acc[VEC];
  #pragma unroll
  for (int v = 0; v < VEC; ++v) acc[v] = 0.f;
  for (int e = beg; e < end; ++e){
    int s = csr[e];
    const T* p = h + (size_t)s * C + lane * VEC;
    if constexpr (sizeof(T) == 4){
      if constexpr (VEC == 2){
        float2 u = *(const float2*)p;
        acc[0] += u.x; acc[1] += u.y;
      } else {
        float4 u = *(const float4*)p;
        acc[0] += u.x; acc[1] += u.y; acc[2] += u.z; acc[3] += u.w;
      }
    } else {
      if constexpr (VEC == 2){
        u32 u = *(const u32*)p;
        acc[0] += b2f((unsigned short)(u & 0xffffu));
        acc[1] += b2f((unsigned short)(u >> 16));
      } else {
        uint2 u = *(const uint2*)p;
        acc[0] += b2f((unsigned short)(u.x & 0xffffu));
        acc[1] += b2f((unsigned short)(u.x >> 16));
        acc[2] += b2f((unsigned short)(u.y & 0xffffu));
        acc[3] += b2f((unsigned short)(u.y >> 16));
      }
    }
  }
  float di = dinv[wid];
  bf16_t* po = outm + (size_t)wid * C + lane * VEC;
  if constexpr (VEC == 2){
    u32 u = (u32)f2b(acc[0] * di) | ((u32)f2b(acc[1] * di) << 16);
    *(u32*)po = u;
  } else {
    uint2 u;
    u.x = (u32)f2b(acc[0] * di) | ((u32)f2b(acc[1] * di) << 16);
    u.y = (u32)f2b(acc[2] * di) | ((u32)f2b(acc[3] * di) << 16);
    *(uint2*)po = u;
  }
}

// ---------------- fused dual-GEMM + bias + BN + ReLU ----------------
// out[M,Cout] = A0@W0 + A1@W1 + bias, optional BN+ReLU
// A0: internal bf16 (agg). A1: TA1 (f32 x or internal bf16 h). W/bias/BN: f32.

#define BM 64
#define BN 64
#define BK 32

template<typename TA1, typename TO>
__global__ __launch_bounds__(256) void sage_gemm_k(
    const bf16_t* __restrict__ A0, const TA1* __restrict__ A1,
    const float* __restrict__ W0, const float* __restrict__ W1,
    const float* __restrict__ bias,
    const float* __restrict__ gamma, const float* __restrict__ beta,
    const float* __restrict__ rmean, const float* __restrict__ rvar,
    TO* __restrict__ out, int M, int K, int Cout, int doBnRelu)
{
  __shared__ float As[BK][BM + 1];
  __shared__ float Bs[BK][BN + 1];
  int t  = threadIdx.x;
  int tx = t & 15, ty = t >> 4;
  int m0 = blockIdx.x * BM;
  int n0 = blockIdx.y * BN;
  float acc[4][4];
  #pragma unroll
  for (int i = 0; i < 4; ++i)
    #pragma unroll
    for (int j = 0; j < 4; ++j) acc[i][j] = 0.f;

  for (int pass = 0; pass < 2; ++pass){
    const float* W = pass ? W1 : W0;
    for (int k0 = 0; k0 < K; k0 += BK){
      #pragma unroll
      for (int i = 0; i < 8; ++i){
        int lin = t + i * 256;
        int r = lin >> 5, c = lin & 31;
        int gr = m0 + r;
        float v = 0.f;
        if (gr < M){
          size_t idx = (size_t)gr * K + (k0 + c);
          v = pass ? cvt(A1[idx]) : b2f(A0[idx]);
        }
        As[c][r] = v;
      }
      #pragma unroll
      for (int i = 0; i < 8; ++i){
        int lin = t + i * 256;
        int r = lin >> 6, c = lin & 63;
        Bs[r][c] = W[(size_t)(k0 + r) * Cout + (n0 + c)];
      }
      __syncthreads();
      #pragma unroll
      for (int k = 0; k < BK; ++k){
        float a[4], b[4];
        #pragma unroll
        for (int i = 0; i < 4; ++i) a[i] = As[k][ty * 4 + i];
        #pragma unroll
        for (int j = 0; j < 4; ++j) b[j] = Bs[k][tx * 4 + j];
        #pragma unroll
        for (int i = 0; i < 4; ++i)
          #pragma unroll
          for (int j = 0; j < 4; ++j)
            acc[i][j] += a[i] * b[j];
      }
      __syncthreads();
    }
  }

  #pragma unroll
  for (int j = 0; j < 4; ++j){
    int col = n0 + tx * 4 + j;
    float bb = bias[col];
    float scale = 1.f, shift = 0.f;
    if (doBnRelu){
      scale = gamma[col] * rsqrtf(rvar[col] + 1e-5f);
      shift = beta[col] - rmean[col] * scale;
    }
    #pragma unroll
    for (int i = 0; i < 4; ++i){
      int row = m0 + ty * 4 + i;
      if (row < M){
        float v = acc[i][j] + bb;
        if (doBnRelu){ v = v * scale + shift; v = fmaxf(v, 0.f); }
        sto(&out[(size_t)row * Cout + col], v);
      }
    }
  }
}

// ---------------- launch ----------------

extern "C" void kernel_launch(void* const* d_in, const int* in_sizes, int n_in,
                              void* d_out, int out_size, void* d_ws, size_t ws_size,
                              hipStream_t stream)
{
  const float* x   = (const float*)d_in[0];
  const int*   ei  = (const int*)d_in[1];
  const float* W1l = (const float*)d_in[2];
  const float* b1l = (const float*)d_in[3];
  const float* W1r = (const float*)d_in[4];
  const float* g1  = (const float*)d_in[5];
  const float* be1 = (const float*)d_in[6];
  const float* rm1 = (const float*)d_in[7];
  const float* rv1 = (const float*)d_in[8];
  const float* W2l = (const float*)d_in[9];
  const float* b2l = (const float*)d_in[10];
  const float* W2r = (const float*)d_in[11];
  const float* g2  = (const float*)d_in[12];
  const float* be2 = (const float*)d_in[13];
  const float* rm2 = (const float*)d_in[14];
  const float* rv2 = (const float*)d_in[15];
  const float* Wcl = (const float*)d_in[16];
  const float* bcl = (const float*)d_in[17];
  const float* Wcr = (const float*)d_in[18];
  (void)in_sizes; (void)n_in; (void)out_size; (void)ws_size;

  char* ws = (char*)d_ws;
  size_t off = 0;
  auto alloc = [&](size_t bytes)->char* {
    char* p = ws + off;
    off += (bytes + 15) & ~(size_t)15;
    return p;
  };
  int*    deg    = (int*)   alloc((size_t)NN * 4);
  int*    fil    = (int*)   alloc((size_t)NN * 4);      // contiguous after deg
  int*    rowptr = (int*)   alloc((size_t)(NN + 1) * 4);
  int*    bsums  = (int*)   alloc(512 * 4);
  int*    eflag  = (int*)   alloc(16);
  int*    csr    = (int*)   alloc((size_t)EE * 4);
  float*  dinv   = (float*) alloc((size_t)NN * 4);
  bf16_t* aggb   = (bf16_t*)alloc((size_t)NN * HID_C * 2);
  bf16_t* h1     = (bf16_t*)alloc((size_t)NN * HID_C * 2);
  bf16_t* h2     = (bf16_t*)alloc((size_t)NN * HID_C * 2);

  // zero deg + fil (adjacent, each NN*4 bytes, 16B-aligned sizes)
  hipMemsetAsync(deg, 0, (size_t)NN * 2 * 4, stream);

  int eb = (EE + 255) / 256;
  int nb = (NN + 255) / 256;   // 391 <= 512
  detect_edge_k<<<1, 256, 0, stream>>>(ei, eflag);
  count_deg_k<<<eb, 256, 0, stream>>>(ei, eflag, deg);
  deginv_k<<<nb, 256, 0, stream>>>(deg, dinv);
  scan1_k<<<nb, 256, 0, stream>>>(deg, rowptr, bsums);
  scan2_k<<<1, 512, 0, stream>>>(bsums, nb);
  scan3_k<<<nb, 256, 0, stream>>>(rowptr, bsums);
  fill_k<<<eb, 256, 0, stream>>>(ei, eflag, rowptr, fil, csr);

  int aggblocks = (NN + 3) / 4;  // 4 waves (nodes) per 256-thread block

  // layer 1: agg over x [N,128] (f32), GEMM -> h1 [N,256] bf16 with BN+ReLU
  agg_mean_k<IN_C, float><<<aggblocks, 256, 0, stream>>>(x, rowptr, csr, dinv, aggb);
  dim3 gdim1((NN + BM - 1) / BM, HID_C / BN);
  sage_gemm_k<float, bf16_t><<<gdim1, 256, 0, stream>>>(
      aggb, x, W1l, W1r, b1l, g1, be1, rm1, rv1, h1, NN, IN_C, HID_C, 1);

  // layer 2: agg over h1 [N,256] bf16, GEMM -> h2 [N,256] bf16 with BN+ReLU
  agg_mean_k<HID_C, bf16_t><<<aggblocks, 256, 0, stream>>>(h1, rowptr, csr, dinv, aggb);
  sage_gemm_k<bf16_t, bf16_t><<<gdim1, 256, 0, stream>>>(
      aggb, h1, W2l, W2r, b2l, g2, be2, rm2, rv2, h2, NN, HID_C, HID_C, 1);

  // layer 3: agg over h2 [N,256] bf16, GEMM -> out [N,64] f32, no BN/ReLU
  agg_mean_k<HID_C, bf16_t><<<aggblocks, 256, 0, stream>>>(h2, rowptr, csr, dinv, aggb);
  dim3 gdim3((NN + BM - 1) / BM, OUT_C / BN);
  sage_gemm_k<bf16_t, float><<<gdim3, 256, 0, stream>>>(
      aggb, h2, Wcl, Wcr, bcl, nullptr, nullptr, nullptr, nullptr,
      (float*)d_out, NN, HID_C, OUT_C, 0);
}

// Round 3
// 939.056 us; speedup vs baseline: 2.4623x; 2.4623x over previous
//
#include <hip/hip_runtime.h>
#include <stdint.h>

#define NN 100000
#define EE 1600000
#define IN_C 128
#define HID_C 256
#define OUT_C 64

typedef unsigned short bf16_t;
typedef unsigned int u32;
typedef __attribute__((ext_vector_type(8))) short bf16x8;
typedef __attribute__((ext_vector_type(4))) float f32x4;

__device__ __forceinline__ float b2f(unsigned short u){
  unsigned int x = ((unsigned int)u) << 16;
  return __uint_as_float(x);
}
__device__ __forceinline__ unsigned short f2b(float f){
  unsigned int x = __float_as_uint(f);
  unsigned int r = x + 0x7FFFu + ((x >> 16) & 1u);   // RNE
  return (unsigned short)(r >> 16);
}
__device__ __forceinline__ void sto(float* p, float v){ *p = v; }
__device__ __forceinline__ void sto(bf16_t* p, float v){ *p = f2b(v); }

// ---------------- edge dtype detector ----------------
__global__ void detect_edge_k(const int* __restrict__ ei, int* __restrict__ eflag){
  __shared__ int sm[256];
  int t = threadIdx.x;
  int o = 0;
  for (int i = t; i < 1024; i += 256) o |= ei[2*i + 1];
  sm[t] = o; __syncthreads();
  for (int s = 128; s > 0; s >>= 1){
    if (t < s) sm[t] |= sm[t + s];
    __syncthreads();
  }
  if (t == 0) *eflag = (sm[0] == 0) ? 1 : 0;   // 1 = int64 layout
}

// ---------------- CSR build ----------------

__global__ void count_deg_k(const int* __restrict__ ei, const int* __restrict__ eflag,
                            int* __restrict__ deg){
  int g = blockIdx.x * blockDim.x + threadIdx.x;
  if (g < EE){
    int i64 = *eflag;
    int d = i64 ? ei[2*(EE + g)] : ei[EE + g];
    atomicAdd(&deg[d], 1);
  }
}

__global__ void deginv_k(const int* __restrict__ deg, float* __restrict__ dinv){
  int g = blockIdx.x * blockDim.x + threadIdx.x;
  if (g < NN){ int d = deg[g]; dinv[g] = d > 0 ? 1.0f / (float)d : 0.0f; }
}

__global__ void scan1_k(const int* __restrict__ deg, int* __restrict__ rowptr,
                        int* __restrict__ bsums){
  __shared__ int sm[256];
  int t = threadIdx.x;
  int g = blockIdx.x * 256 + t;
  int v = (g < NN) ? deg[g] : 0;
  sm[t] = v; __syncthreads();
  for (int off = 1; off < 256; off <<= 1){
    int add = (t >= off) ? sm[t - off] : 0;
    __syncthreads();
    sm[t] += add;
    __syncthreads();
  }
  if (g < NN) rowptr[g + 1] = sm[t];
  if (t == 255) bsums[blockIdx.x] = sm[255];
}

__global__ void scan2_k(int* __restrict__ bsums, int nb){
  __shared__ int sm[512];
  int t = threadIdx.x;
  sm[t] = (t < nb) ? bsums[t] : 0; __syncthreads();
  for (int off = 1; off < 512; off <<= 1){
    int add = (t >= off) ? sm[t - off] : 0;
    __syncthreads();
    sm[t] += add;
    __syncthreads();
  }
  if (t < nb) bsums[t] = sm[t];
}

__global__ void scan3_k(int* __restrict__ rowptr, const int* __restrict__ bsums){
  int g = blockIdx.x * 256 + threadIdx.x;
  if (g < NN && blockIdx.x > 0) rowptr[g + 1] += bsums[blockIdx.x - 1];
  if (g == 0) rowptr[0] = 0;
}

__global__ void fill_k(const int* __restrict__ ei, const int* __restrict__ eflag,
                       const int* __restrict__ rowptr, int* __restrict__ fill,
                       int* __restrict__ csr){
  int g = blockIdx.x * blockDim.x + threadIdx.x;
  if (g < EE){
    int i64 = *eflag;
    int s = i64 ? ei[2*g]          : ei[g];
    int d = i64 ? ei[2*(EE + g)]   : ei[EE + g];
    int pos = rowptr[d] + atomicAdd(&fill[d], 1);
    csr[pos] = s;
  }
}

// ---------------- dtype conversion ----------------

// f32 -> bf16, n divisible by 4
__global__ void f2b_vec_k(const float* __restrict__ in, bf16_t* __restrict__ out, int n){
  int g = blockIdx.x * 256 + threadIdx.x;
  int i = g * 4;
  if (i < n){
    float4 v = *(const float4*)(in + i);
    uint2 u;
    u.x = (u32)f2b(v.x) | ((u32)f2b(v.y) << 16);
    u.y = (u32)f2b(v.z) | ((u32)f2b(v.w) << 16);
    *(uint2*)(out + i) = u;
  }
}

// W [K,N] f32 -> Wt [N,K] bf16 (transposed); coalesced writes
__global__ void wt_t_k(const float* __restrict__ W, bf16_t* __restrict__ Wt, int K, int N){
  int g = blockIdx.x * 256 + threadIdx.x;
  if (g < K * N){
    int n = g / K, k = g - n * K;
    Wt[g] = f2b(W[(size_t)k * N + n]);
  }
}

// ---------------- mean aggregation: one wave per node, bf16 rows ----------------

template<int C>
__global__ __launch_bounds__(256) void agg_mean_k(const bf16_t* __restrict__ h,
    const int* __restrict__ rowptr, const int* __restrict__ csr,
    const float* __restrict__ dinv, bf16_t* __restrict__ outm){
  constexpr int VEC = C / 64;                 // 2 (C=128) or 4 (C=256)
  int wid  = (blockIdx.x * 256 + threadIdx.x) >> 6;
  int lane = threadIdx.x & 63;
  if (wid >= NN) return;
  int beg = rowptr[wid], end = rowptr[wid + 1];
  float acc[VEC];
  #pragma unroll
  for (int v = 0; v < VEC; ++v) acc[v] = 0.f;
  int e = beg;
  for (; e + 1 < end; e += 2){                 // 2-edge unroll: 2 loads in flight
    int s0 = csr[e], s1 = csr[e + 1];
    if constexpr (VEC == 2){
      u32 u0 = *(const u32*)(h + (size_t)s0 * C + lane * 2);
      u32 u1 = *(const u32*)(h + (size_t)s1 * C + lane * 2);
      acc[0] += b2f((unsigned short)(u0 & 0xffffu)) + b2f((unsigned short)(u1 & 0xffffu));
      acc[1] += b2f((unsigned short)(u0 >> 16))     + b2f((unsigned short)(u1 >> 16));
    } else {
      uint2 u0 = *(const uint2*)(h + (size_t)s0 * C + lane * 4);
      uint2 u1 = *(const uint2*)(h + (size_t)s1 * C + lane * 4);
      acc[0] += b2f((unsigned short)(u0.x & 0xffffu)) + b2f((unsigned short)(u1.x & 0xffffu));
      acc[1] += b2f((unsigned short)(u0.x >> 16))     + b2f((unsigned short)(u1.x >> 16));
      acc[2] += b2f((unsigned short)(u0.y & 0xffffu)) + b2f((unsigned short)(u1.y & 0xffffu));
      acc[3] += b2f((unsigned short)(u0.y >> 16))     + b2f((unsigned short)(u1.y >> 16));
    }
  }
  if (e < end){
    int s0 = csr[e];
    if constexpr (VEC == 2){
      u32 u0 = *(const u32*)(h + (size_t)s0 * C + lane * 2);
      acc[0] += b2f((unsigned short)(u0 & 0xffffu));
      acc[1] += b2f((unsigned short)(u0 >> 16));
    } else {
      uint2 u0 = *(const uint2*)(h + (size_t)s0 * C + lane * 4);
      acc[0] += b2f((unsigned short)(u0.x & 0xffffu));
      acc[1] += b2f((unsigned short)(u0.x >> 16));
      acc[2] += b2f((unsigned short)(u0.y & 0xffffu));
      acc[3] += b2f((unsigned short)(u0.y >> 16));
    }
  }
  float di = dinv[wid];
  bf16_t* po = outm + (size_t)wid * C + lane * VEC;
  if constexpr (VEC == 2){
    u32 u = (u32)f2b(acc[0] * di) | ((u32)f2b(acc[1] * di) << 16);
    *(u32*)po = u;
  } else {
    uint2 u;
    u.x = (u32)f2b(acc[0] * di) | ((u32)f2b(acc[1] * di) << 16);
    u.y = (u32)f2b(acc[2] * di) | ((u32)f2b(acc[3] * di) << 16);
    *(uint2*)po = u;
  }
}

// ---------------- MFMA dual-GEMM + bias + BN + ReLU ----------------
// out[M,Nout] = A0@W0 + A1@W1 + bias (+BN+ReLU). A row-major [M,K] bf16,
// W*t transposed [N][K] bf16. 128xBN tile, 4 waves (2x2), 16x16x32 MFMA.

template<int BN, int NT_N, typename TO>
__global__ __launch_bounds__(256) void mfma_gemm_k(
    const bf16_t* __restrict__ A0, const bf16_t* __restrict__ A1,
    const bf16_t* __restrict__ W0t, const bf16_t* __restrict__ W1t,
    const float* __restrict__ bias,
    const float* __restrict__ gamma, const float* __restrict__ beta,
    const float* __restrict__ rmean, const float* __restrict__ rvar,
    TO* __restrict__ out, int M, int K, int Nout, int doBnRelu)
{
  constexpr int BM = 128;
  constexpr int BK = 32;
  constexpr int LDA = BK + 8;                  // 80B row stride: 2-way bank alias max
  __shared__ bf16_t As[BM * LDA];
  __shared__ bf16_t Bs[BN * LDA];

  int t    = threadIdx.x;
  int lane = t & 63;
  int wid  = t >> 6;
  int wr   = wid >> 1, wc = wid & 1;
  int l15  = lane & 15;
  int quad = lane >> 4;

  int m0 = blockIdx.x * BM;
  int n0 = blockIdx.y * BN;

  f32x4 acc[4][NT_N];
  #pragma unroll
  for (int i = 0; i < 4; ++i)
    #pragma unroll
    for (int j = 0; j < NT_N; ++j)
      acc[i][j] = (f32x4){0.f, 0.f, 0.f, 0.f};

  for (int pass = 0; pass < 2; ++pass){
    const bf16_t* A  = pass ? A1 : A0;
    const bf16_t* Wt = pass ? W1t : W0t;
    for (int k0 = 0; k0 < K; k0 += BK){
      // stage A tile [BM][BK]
      #pragma unroll
      for (int c = t; c < BM * 4; c += 256){
        int row = c >> 2, k8 = c & 3;
        uint4 v = make_uint4(0u, 0u, 0u, 0u);
        int gm = m0 + row;
        if (gm < M) v = *(const uint4*)(A + (size_t)gm * K + k0 + k8 * 8);
        *(uint4*)(As + row * LDA + k8 * 8) = v;
      }
      // stage B tile [BN][BK] from transposed weights
      #pragma unroll
      for (int c = t; c < BN * 4; c += 256){
        int row = c >> 2, k8 = c & 3;
        uint4 v = *(const uint4*)(Wt + (size_t)(n0 + row) * K + k0 + k8 * 8);
        *(uint4*)(Bs + row * LDA + k8 * 8) = v;
      }
      __syncthreads();
      bf16x8 af[4], bfr[NT_N];
      #pragma unroll
      for (int i = 0; i < 4; ++i)
        af[i] = *(const bf16x8*)(As + (wr * 64 + i * 16 + l15) * LDA + quad * 8);
      #pragma unroll
      for (int j = 0; j < NT_N; ++j)
        bfr[j] = *(const bf16x8*)(Bs + (wc * (NT_N * 16) + j * 16 + l15) * LDA + quad * 8);
      #pragma unroll
      for (int i = 0; i < 4; ++i)
        #pragma unroll
        for (int j = 0; j < NT_N; ++j)
          acc[i][j] = __builtin_amdgcn_mfma_f32_16x16x32_bf16(af[i], bfr[j], acc[i][j], 0, 0, 0);
      __syncthreads();
    }
  }

  // epilogue: C/D layout col=lane&15, row=quad*4+reg
  #pragma unroll
  for (int j = 0; j < NT_N; ++j){
    int col = n0 + wc * (NT_N * 16) + j * 16 + l15;
    float bb = bias[col];
    float scale = 1.f, shift = bb;
    if (doBnRelu){
      float sc = gamma[col] * rsqrtf(rvar[col] + 1e-5f);
      scale = sc;
      shift = (bb - rmean[col]) * sc + beta[col];
    }
    #pragma unroll
    for (int i = 0; i < 4; ++i){
      int rbase = m0 + wr * 64 + i * 16 + quad * 4;
      #pragma unroll
      for (int r = 0; r < 4; ++r){
        int row = rbase + r;
        if (row < M){
          float v = acc[i][j][r] * scale + shift;
          if (doBnRelu) v = fmaxf(v, 0.f);
          sto(&out[(size_t)row * Nout + col], v);
        }
      }
    }
  }
}

// ---------------- launch ----------------

extern "C" void kernel_launch(void* const* d_in, const int* in_sizes, int n_in,
                              void* d_out, int out_size, void* d_ws, size_t ws_size,
                              hipStream_t stream)
{
  const float* x   = (const float*)d_in[0];
  const int*   ei  = (const int*)d_in[1];
  const float* W1l = (const float*)d_in[2];
  const float* b1l = (const float*)d_in[3];
  const float* W1r = (const float*)d_in[4];
  const float* g1  = (const float*)d_in[5];
  const float* be1 = (const float*)d_in[6];
  const float* rm1 = (const float*)d_in[7];
  const float* rv1 = (const float*)d_in[8];
  const float* W2l = (const float*)d_in[9];
  const float* b2l = (const float*)d_in[10];
  const float* W2r = (const float*)d_in[11];
  const float* g2  = (const float*)d_in[12];
  const float* be2 = (const float*)d_in[13];
  const float* rm2 = (const float*)d_in[14];
  const float* rv2 = (const float*)d_in[15];
  const float* Wcl = (const float*)d_in[16];
  const float* bcl = (const float*)d_in[17];
  const float* Wcr = (const float*)d_in[18];
  (void)in_sizes; (void)n_in; (void)out_size; (void)ws_size;

  char* ws = (char*)d_ws;
  size_t off = 0;
  auto alloc = [&](size_t bytes)->char* {
    char* p = ws + off;
    off += (bytes + 15) & ~(size_t)15;
    return p;
  };
  int*    deg    = (int*)   alloc((size_t)NN * 4);
  int*    fil    = (int*)   alloc((size_t)NN * 4);      // contiguous after deg
  int*    rowptr = (int*)   alloc((size_t)(NN + 1) * 4);
  int*    bsums  = (int*)   alloc(512 * 4);
  int*    eflag  = (int*)   alloc(16);
  int*    csr    = (int*)   alloc((size_t)EE * 4);
  float*  dinv   = (float*) alloc((size_t)NN * 4);
  bf16_t* xb     = (bf16_t*)alloc((size_t)NN * IN_C * 2);
  bf16_t* aggb   = (bf16_t*)alloc((size_t)NN * HID_C * 2);
  bf16_t* h1     = (bf16_t*)alloc((size_t)NN * HID_C * 2);
  bf16_t* h2     = (bf16_t*)alloc((size_t)NN * HID_C * 2);
  bf16_t* W1lt   = (bf16_t*)alloc((size_t)IN_C  * HID_C * 2);
  bf16_t* W1rt   = (bf16_t*)alloc((size_t)IN_C  * HID_C * 2);
  bf16_t* W2lt   = (bf16_t*)alloc((size_t)HID_C * HID_C * 2);
  bf16_t* W2rt   = (bf16_t*)alloc((size_t)HID_C * HID_C * 2);
  bf16_t* Wclt   = (bf16_t*)alloc((size_t)HID_C * OUT_C * 2);
  bf16_t* Wcrt   = (bf16_t*)alloc((size_t)HID_C * OUT_C * 2);

  hipMemsetAsync(deg, 0, (size_t)NN * 2 * 4, stream);

  int eb = (EE + 255) / 256;
  int nb = (NN + 255) / 256;

  // conversions
  f2b_vec_k<<<(NN * IN_C / 4 + 255) / 256, 256, 0, stream>>>(x, xb, NN * IN_C);
  wt_t_k<<<(IN_C * HID_C + 255) / 256, 256, 0, stream>>>(W1l, W1lt, IN_C, HID_C);
  wt_t_k<<<(IN_C * HID_C + 255) / 256, 256, 0, stream>>>(W1r, W1rt, IN_C, HID_C);
  wt_t_k<<<(HID_C * HID_C + 255) / 256, 256, 0, stream>>>(W2l, W2lt, HID_C, HID_C);
  wt_t_k<<<(HID_C * HID_C + 255) / 256, 256, 0, stream>>>(W2r, W2rt, HID_C, HID_C);
  wt_t_k<<<(HID_C * OUT_C + 255) / 256, 256, 0, stream>>>(Wcl, Wclt, HID_C, OUT_C);
  wt_t_k<<<(HID_C * OUT_C + 255) / 256, 256, 0, stream>>>(Wcr, Wcrt, HID_C, OUT_C);

  // CSR
  detect_edge_k<<<1, 256, 0, stream>>>(ei, eflag);
  count_deg_k<<<eb, 256, 0, stream>>>(ei, eflag, deg);
  deginv_k<<<nb, 256, 0, stream>>>(deg, dinv);
  scan1_k<<<nb, 256, 0, stream>>>(deg, rowptr, bsums);
  scan2_k<<<1, 512, 0, stream>>>(bsums, nb);
  scan3_k<<<nb, 256, 0, stream>>>(rowptr, bsums);
  fill_k<<<eb, 256, 0, stream>>>(ei, eflag, rowptr, fil, csr);

  int aggblocks = (NN + 3) / 4;
  int mblocks   = (NN + 127) / 128;

  // layer 1: agg over xb [N,128], GEMM -> h1 [N,256] bf16, BN+ReLU
  agg_mean_k<IN_C><<<aggblocks, 256, 0, stream>>>(xb, rowptr, csr, dinv, aggb);
  dim3 g1d(mblocks, HID_C / 128);
  mfma_gemm_k<128, 4, bf16_t><<<g1d, 256, 0, stream>>>(
      aggb, xb, W1lt, W1rt, b1l, g1, be1, rm1, rv1, h1, NN, IN_C, HID_C, 1);

  // layer 2: agg over h1 [N,256], GEMM -> h2 [N,256] bf16, BN+ReLU
  agg_mean_k<HID_C><<<aggblocks, 256, 0, stream>>>(h1, rowptr, csr, dinv, aggb);
  mfma_gemm_k<128, 4, bf16_t><<<g1d, 256, 0, stream>>>(
      aggb, h1, W2lt, W2rt, b2l, g2, be2, rm2, rv2, h2, NN, HID_C, HID_C, 1);

  // layer 3: agg over h2 [N,256], GEMM -> out [N,64] f32
  agg_mean_k<HID_C><<<aggblocks, 256, 0, stream>>>(h2, rowptr, csr, dinv, aggb);
  dim3 g3d(mblocks, 1);
  mfma_gemm_k<64, 2, float><<<g3d, 256, 0, stream>>>(
      aggb, h2, Wclt, Wcrt, bcl, nullptr, nullptr, nullptr, nullptr,
      (float*)d_out, NN, HID_C, OUT_C, 0);
}

// Round 4
// 789.547 us; speedup vs baseline: 2.9286x; 1.1894x over previous
//
#include <hip/hip_runtime.h>
#include <stdint.h>

#define NN 100000
#define EE 1600000
#define IN_C 128
#define HID_C 256
#define OUT_C 64

typedef unsigned short bf16_t;
typedef unsigned int u32;
typedef __attribute__((ext_vector_type(8))) short bf16x8;
typedef __attribute__((ext_vector_type(4))) float f32x4;

__device__ __forceinline__ float b2f(unsigned short u){
  unsigned int x = ((unsigned int)u) << 16;
  return __uint_as_float(x);
}
__device__ __forceinline__ unsigned short f2b(float f){
  unsigned int x = __float_as_uint(f);
  unsigned int r = x + 0x7FFFu + ((x >> 16) & 1u);   // RNE
  return (unsigned short)(r >> 16);
}

// ---------------- edge dtype detector ----------------
__global__ void detect_edge_k(const int* __restrict__ ei, int* __restrict__ eflag){
  __shared__ int sm[256];
  int t = threadIdx.x;
  int o = 0;
  for (int i = t; i < 1024; i += 256) o |= ei[2*i + 1];
  sm[t] = o; __syncthreads();
  for (int s = 128; s > 0; s >>= 1){
    if (t < s) sm[t] |= sm[t + s];
    __syncthreads();
  }
  if (t == 0) *eflag = (sm[0] == 0) ? 1 : 0;   // 1 = int64 layout
}

// ---------------- CSR build ----------------

__global__ void count_deg_k(const int* __restrict__ ei, const int* __restrict__ eflag,
                            int* __restrict__ deg){
  int g = blockIdx.x * blockDim.x + threadIdx.x;
  if (g < EE){
    int i64 = *eflag;
    int d = i64 ? ei[2*(EE + g)] : ei[EE + g];
    atomicAdd(&deg[d], 1);
  }
}

__global__ void scan1_k(const int* __restrict__ deg, int* __restrict__ rowptr,
                        int* __restrict__ bsums){
  __shared__ int sm[256];
  int t = threadIdx.x;
  int g = blockIdx.x * 256 + t;
  int v = (g < NN) ? deg[g] : 0;
  sm[t] = v; __syncthreads();
  for (int off = 1; off < 256; off <<= 1){
    int add = (t >= off) ? sm[t - off] : 0;
    __syncthreads();
    sm[t] += add;
    __syncthreads();
  }
  if (g < NN) rowptr[g + 1] = sm[t];
  if (t == 255) bsums[blockIdx.x] = sm[255];
}

__global__ void scan2_k(int* __restrict__ bsums, int nb){
  __shared__ int sm[512];
  int t = threadIdx.x;
  sm[t] = (t < nb) ? bsums[t] : 0; __syncthreads();
  for (int off = 1; off < 512; off <<= 1){
    int add = (t >= off) ? sm[t - off] : 0;
    __syncthreads();
    sm[t] += add;
    __syncthreads();
  }
  if (t < nb) bsums[t] = sm[t];
}

__global__ void scan3_k(int* __restrict__ rowptr, const int* __restrict__ bsums){
  int g = blockIdx.x * 256 + threadIdx.x;
  if (g < NN && blockIdx.x > 0) rowptr[g + 1] += bsums[blockIdx.x - 1];
  if (g == 0) rowptr[0] = 0;
}

__global__ void fill_k(const int* __restrict__ ei, const int* __restrict__ eflag,
                       const int* __restrict__ rowptr, int* __restrict__ fill,
                       int* __restrict__ csr){
  int g = blockIdx.x * blockDim.x + threadIdx.x;
  if (g < EE){
    int i64 = *eflag;
    int s = i64 ? ei[2*g]          : ei[g];
    int d = i64 ? ei[2*(EE + g)]   : ei[EE + g];
    int pos = rowptr[d] + atomicAdd(&fill[d], 1);
    csr[pos] = s;
  }
}

// ---------------- dtype conversion ----------------

// f32 -> bf16, n divisible by 4
__global__ void f2b_vec_k(const float* __restrict__ in, bf16_t* __restrict__ out, int n){
  int g = blockIdx.x * 256 + threadIdx.x;
  int i = g * 4;
  if (i < n){
    float4 v = *(const float4*)(in + i);
    uint2 u;
    u.x = (u32)f2b(v.x) | ((u32)f2b(v.y) << 16);
    u.y = (u32)f2b(v.z) | ((u32)f2b(v.w) << 16);
    *(uint2*)(out + i) = u;
  }
}

// all-in-one weight transpose: W[K,N] f32 -> Wt[N,K] bf16 for 6 weights
struct WtArgs {
  const float* W[6];
  bf16_t* Wt[6];
  int K[6], N[6];
  int off[7];
};

__global__ void wt_all_k(WtArgs a){
  int g = blockIdx.x * 256 + threadIdx.x;
  if (g >= a.off[6]) return;
  #pragma unroll
  for (int s = 0; s < 6; ++s){
    if (g >= a.off[s] && g < a.off[s + 1]){
      int local = g - a.off[s];
      int K = a.K[s], N = a.N[s];
      int n = local / K, k = local - n * K;
      a.Wt[s][local] = f2b(a.W[s][(size_t)k * N + n]);
    }
  }
}

// ---------------- mean aggregation: one wave per node, bf16 rows ----------------
// deg_inv derived from rowptr; 4-edge unroll for MLP.

template<int C>
__global__ __launch_bounds__(256) void agg_mean_k(const bf16_t* __restrict__ h,
    const int* __restrict__ rowptr, const int* __restrict__ csr,
    bf16_t* __restrict__ outm){
  constexpr int VEC = C / 64;                 // 2 (C=128) or 4 (C=256)
  int wid  = (blockIdx.x * 256 + threadIdx.x) >> 6;
  int lane = threadIdx.x & 63;
  if (wid >= NN) return;
  int beg = rowptr[wid], end = rowptr[wid + 1];
  float acc[VEC];
  #pragma unroll
  for (int v = 0; v < VEC; ++v) acc[v] = 0.f;
  int e = beg;
  for (; e + 3 < end; e += 4){
    int s0 = csr[e], s1 = csr[e+1], s2 = csr[e+2], s3 = csr[e+3];
    if constexpr (VEC == 2){
      u32 u0 = *(const u32*)(h + (size_t)s0 * C + lane * 2);
      u32 u1 = *(const u32*)(h + (size_t)s1 * C + lane * 2);
      u32 u2 = *(const u32*)(h + (size_t)s2 * C + lane * 2);
      u32 u3 = *(const u32*)(h + (size_t)s3 * C + lane * 2);
      acc[0] += (b2f((unsigned short)(u0 & 0xffffu)) + b2f((unsigned short)(u1 & 0xffffu)))
              + (b2f((unsigned short)(u2 & 0xffffu)) + b2f((unsigned short)(u3 & 0xffffu)));
      acc[1] += (b2f((unsigned short)(u0 >> 16)) + b2f((unsigned short)(u1 >> 16)))
              + (b2f((unsigned short)(u2 >> 16)) + b2f((unsigned short)(u3 >> 16)));
    } else {
      uint2 u0 = *(const uint2*)(h + (size_t)s0 * C + lane * 4);
      uint2 u1 = *(const uint2*)(h + (size_t)s1 * C + lane * 4);
      uint2 u2 = *(const uint2*)(h + (size_t)s2 * C + lane * 4);
      uint2 u3 = *(const uint2*)(h + (size_t)s3 * C + lane * 4);
      acc[0] += (b2f((unsigned short)(u0.x & 0xffffu)) + b2f((unsigned short)(u1.x & 0xffffu)))
              + (b2f((unsigned short)(u2.x & 0xffffu)) + b2f((unsigned short)(u3.x & 0xffffu)));
      acc[1] += (b2f((unsigned short)(u0.x >> 16)) + b2f((unsigned short)(u1.x >> 16)))
              + (b2f((unsigned short)(u2.x >> 16)) + b2f((unsigned short)(u3.x >> 16)));
      acc[2] += (b2f((unsigned short)(u0.y & 0xffffu)) + b2f((unsigned short)(u1.y & 0xffffu)))
              + (b2f((unsigned short)(u2.y & 0xffffu)) + b2f((unsigned short)(u3.y & 0xffffu)));
      acc[3] += (b2f((unsigned short)(u0.y >> 16)) + b2f((unsigned short)(u1.y >> 16)))
              + (b2f((unsigned short)(u2.y >> 16)) + b2f((unsigned short)(u3.y >> 16)));
    }
  }
  for (; e < end; ++e){
    int s0 = csr[e];
    if constexpr (VEC == 2){
      u32 u0 = *(const u32*)(h + (size_t)s0 * C + lane * 2);
      acc[0] += b2f((unsigned short)(u0 & 0xffffu));
      acc[1] += b2f((unsigned short)(u0 >> 16));
    } else {
      uint2 u0 = *(const uint2*)(h + (size_t)s0 * C + lane * 4);
      acc[0] += b2f((unsigned short)(u0.x & 0xffffu));
      acc[1] += b2f((unsigned short)(u0.x >> 16));
      acc[2] += b2f((unsigned short)(u0.y & 0xffffu));
      acc[3] += b2f((unsigned short)(u0.y >> 16));
    }
  }
  int d = end - beg;
  float di = d > 0 ? 1.0f / (float)d : 0.f;
  bf16_t* po = outm + (size_t)wid * C + lane * VEC;
  if constexpr (VEC == 2){
    u32 u = (u32)f2b(acc[0] * di) | ((u32)f2b(acc[1] * di) << 16);
    *(u32*)po = u;
  } else {
    uint2 u;
    u.x = (u32)f2b(acc[0] * di) | ((u32)f2b(acc[1] * di) << 16);
    u.y = (u32)f2b(acc[2] * di) | ((u32)f2b(acc[3] * di) << 16);
    *(uint2*)po = u;
  }
}

// ---------------- final aggregation (layer 3, C=64) ----------------
// out[n,c] = dinv(n) * sum_src P[src,c] + Q[n,c]

__global__ __launch_bounds__(256) void agg_final_k(
    const bf16_t* __restrict__ P, const float* __restrict__ Q,
    const int* __restrict__ rowptr, const int* __restrict__ csr,
    float* __restrict__ out){
  int wid  = (blockIdx.x * 256 + threadIdx.x) >> 6;
  int lane = threadIdx.x & 63;
  if (wid >= NN) return;
  int beg = rowptr[wid], end = rowptr[wid + 1];
  float acc = 0.f;
  int e = beg;
  for (; e + 3 < end; e += 4){
    int s0 = csr[e], s1 = csr[e+1], s2 = csr[e+2], s3 = csr[e+3];
    float a0 = b2f(P[(size_t)s0 * 64 + lane]);
    float a1 = b2f(P[(size_t)s1 * 64 + lane]);
    float a2 = b2f(P[(size_t)s2 * 64 + lane]);
    float a3 = b2f(P[(size_t)s3 * 64 + lane]);
    acc += (a0 + a1) + (a2 + a3);
  }
  for (; e < end; ++e) acc += b2f(P[(size_t)csr[e] * 64 + lane]);
  int d = end - beg;
  float di = d > 0 ? 1.0f / (float)d : 0.f;
  out[(size_t)wid * 64 + lane] = acc * di + Q[(size_t)wid * 64 + lane];
}

// ---------------- MFMA dual-GEMM + bias + BN + ReLU (layers 1,2) ----------------

template<int BN, int NT_N>
__global__ __launch_bounds__(256) void mfma_gemm_k(
    const bf16_t* __restrict__ A0, const bf16_t* __restrict__ A1,
    const bf16_t* __restrict__ W0t, const bf16_t* __restrict__ W1t,
    const float* __restrict__ bias,
    const float* __restrict__ gamma, const float* __restrict__ beta,
    const float* __restrict__ rmean, const float* __restrict__ rvar,
    bf16_t* __restrict__ out, int M, int K, int Nout)
{
  constexpr int BM = 128;
  constexpr int BK = 32;
  constexpr int LDA = BK + 8;
  __shared__ bf16_t As[BM * LDA];
  __shared__ bf16_t Bs[BN * LDA];

  int t    = threadIdx.x;
  int lane = t & 63;
  int wid  = t >> 6;
  int wr   = wid >> 1, wc = wid & 1;
  int l15  = lane & 15;
  int quad = lane >> 4;

  int m0 = blockIdx.x * BM;
  int n0 = blockIdx.y * BN;

  f32x4 acc[4][NT_N];
  #pragma unroll
  for (int i = 0; i < 4; ++i)
    #pragma unroll
    for (int j = 0; j < NT_N; ++j)
      acc[i][j] = (f32x4){0.f, 0.f, 0.f, 0.f};

  for (int pass = 0; pass < 2; ++pass){
    const bf16_t* A  = pass ? A1 : A0;
    const bf16_t* Wt = pass ? W1t : W0t;
    for (int k0 = 0; k0 < K; k0 += BK){
      #pragma unroll
      for (int c = t; c < BM * 4; c += 256){
        int row = c >> 2, k8 = c & 3;
        uint4 v = make_uint4(0u, 0u, 0u, 0u);
        int gm = m0 + row;
        if (gm < M) v = *(const uint4*)(A + (size_t)gm * K + k0 + k8 * 8);
        *(uint4*)(As + row * LDA + k8 * 8) = v;
      }
      #pragma unroll
      for (int c = t; c < BN * 4; c += 256){
        int row = c >> 2, k8 = c & 3;
        uint4 v = *(const uint4*)(Wt + (size_t)(n0 + row) * K + k0 + k8 * 8);
        *(uint4*)(Bs + row * LDA + k8 * 8) = v;
      }
      __syncthreads();
      bf16x8 af[4], bfr[NT_N];
      #pragma unroll
      for (int i = 0; i < 4; ++i)
        af[i] = *(const bf16x8*)(As + (wr * 64 + i * 16 + l15) * LDA + quad * 8);
      #pragma unroll
      for (int j = 0; j < NT_N; ++j)
        bfr[j] = *(const bf16x8*)(Bs + (wc * (NT_N * 16) + j * 16 + l15) * LDA + quad * 8);
      #pragma unroll
      for (int i = 0; i < 4; ++i)
        #pragma unroll
        for (int j = 0; j < NT_N; ++j)
          acc[i][j] = __builtin_amdgcn_mfma_f32_16x16x32_bf16(af[i], bfr[j], acc[i][j], 0, 0, 0);
      __syncthreads();
    }
  }

  #pragma unroll
  for (int j = 0; j < NT_N; ++j){
    int col = n0 + wc * (NT_N * 16) + j * 16 + l15;
    float sc = gamma[col] * rsqrtf(rvar[col] + 1e-5f);
    float shift = (bias[col] - rmean[col]) * sc + beta[col];
    #pragma unroll
    for (int i = 0; i < 4; ++i){
      int rbase = m0 + wr * 64 + i * 16 + quad * 4;
      #pragma unroll
      for (int r = 0; r < 4; ++r){
        int row = rbase + r;
        if (row < M){
          float v = fmaxf(acc[i][j][r] * sc + shift, 0.f);
          out[(size_t)row * Nout + col] = f2b(v);
        }
      }
    }
  }
}

// ---------------- layer-3 single-A GEMM: P = A@Wcl (bf16), Q = A@Wcr + bcl (f32) ----------------
// Wt is the concat [128][256]: rows 0..63 = Wcl^T, rows 64..127 = Wcr^T

__global__ __launch_bounds__(256) void gemm3_k(
    const bf16_t* __restrict__ A, const bf16_t* __restrict__ Wt,
    const float* __restrict__ bcl,
    bf16_t* __restrict__ P, float* __restrict__ Q, int M)
{
  constexpr int BM = 128, BN = 128, BK = 32, K = 256;
  constexpr int LDA = BK + 8;
  __shared__ bf16_t As[BM * LDA];
  __shared__ bf16_t Bs[BN * LDA];

  int t    = threadIdx.x;
  int lane = t & 63;
  int wid  = t >> 6;
  int wr   = wid >> 1, wc = wid & 1;
  int l15  = lane & 15;
  int quad = lane >> 4;
  int m0 = blockIdx.x * BM;

  f32x4 acc[4][4];
  #pragma unroll
  for (int i = 0; i < 4; ++i)
    #pragma unroll
    for (int j = 0; j < 4; ++j)
      acc[i][j] = (f32x4){0.f, 0.f, 0.f, 0.f};

  for (int k0 = 0; k0 < K; k0 += BK){
    #pragma unroll
    for (int c = t; c < BM * 4; c += 256){
      int row = c >> 2, k8 = c & 3;
      uint4 v = make_uint4(0u, 0u, 0u, 0u);
      int gm = m0 + row;
      if (gm < M) v = *(const uint4*)(A + (size_t)gm * K + k0 + k8 * 8);
      *(uint4*)(As + row * LDA + k8 * 8) = v;
    }
    #pragma unroll
    for (int c = t; c < BN * 4; c += 256){
      int row = c >> 2, k8 = c & 3;
      uint4 v = *(const uint4*)(Wt + (size_t)row * K + k0 + k8 * 8);
      *(uint4*)(Bs + row * LDA + k8 * 8) = v;
    }
    __syncthreads();
    bf16x8 af[4], bfr[4];
    #pragma unroll
    for (int i = 0; i < 4; ++i)
      af[i] = *(const bf16x8*)(As + (wr * 64 + i * 16 + l15) * LDA + quad * 8);
    #pragma unroll
    for (int j = 0; j < 4; ++j)
      bfr[j] = *(const bf16x8*)(Bs + (wc * 64 + j * 16 + l15) * LDA + quad * 8);
    #pragma unroll
    for (int i = 0; i < 4; ++i)
      #pragma unroll
      for (int j = 0; j < 4; ++j)
        acc[i][j] = __builtin_amdgcn_mfma_f32_16x16x32_bf16(af[i], bfr[j], acc[i][j], 0, 0, 0);
    __syncthreads();
  }

  #pragma unroll
  for (int j = 0; j < 4; ++j){
    int col = wc * 64 + j * 16 + l15;      // 0..127
    #pragma unroll
    for (int i = 0; i < 4; ++i){
      int rbase = m0 + wr * 64 + i * 16 + quad * 4;
      #pragma unroll
      for (int r = 0; r < 4; ++r){
        int row = rbase + r;
        if (row < M){
          float v = acc[i][j][r];
          if (col < 64) P[(size_t)row * 64 + col] = f2b(v);
          else          Q[(size_t)row * 64 + (col - 64)] = v + bcl[col - 64];
        }
      }
    }
  }
}

// ---------------- launch ----------------

extern "C" void kernel_launch(void* const* d_in, const int* in_sizes, int n_in,
                              void* d_out, int out_size, void* d_ws, size_t ws_size,
                              hipStream_t stream)
{
  const float* x   = (const float*)d_in[0];
  const int*   ei  = (const int*)d_in[1];
  const float* W1l = (const float*)d_in[2];
  const float* b1l = (const float*)d_in[3];
  const float* W1r = (const float*)d_in[4];
  const float* g1  = (const float*)d_in[5];
  const float* be1 = (const float*)d_in[6];
  const float* rm1 = (const float*)d_in[7];
  const float* rv1 = (const float*)d_in[8];
  const float* W2l = (const float*)d_in[9];
  const float* b2l = (const float*)d_in[10];
  const float* W2r = (const float*)d_in[11];
  const float* g2  = (const float*)d_in[12];
  const float* be2 = (const float*)d_in[13];
  const float* rm2 = (const float*)d_in[14];
  const float* rv2 = (const float*)d_in[15];
  const float* Wcl = (const float*)d_in[16];
  const float* bcl = (const float*)d_in[17];
  const float* Wcr = (const float*)d_in[18];
  (void)in_sizes; (void)n_in; (void)out_size; (void)ws_size;

  char* ws = (char*)d_ws;
  size_t off = 0;
  auto alloc = [&](size_t bytes)->char* {
    char* p = ws + off;
    off += (bytes + 15) & ~(size_t)15;
    return p;
  };
  int*    deg    = (int*)   alloc((size_t)NN * 4);
  int*    fil    = (int*)   alloc((size_t)NN * 4);      // contiguous after deg
  int*    rowptr = (int*)   alloc((size_t)(NN + 1) * 4);
  int*    bsums  = (int*)   alloc(512 * 4);
  int*    eflag  = (int*)   alloc(16);
  int*    csr    = (int*)   alloc((size_t)EE * 4);
  bf16_t* xb     = (bf16_t*)alloc((size_t)NN * IN_C * 2);
  bf16_t* aggb   = (bf16_t*)alloc((size_t)NN * HID_C * 2);
  bf16_t* h1     = (bf16_t*)alloc((size_t)NN * HID_C * 2);
  bf16_t* h2     = (bf16_t*)alloc((size_t)NN * HID_C * 2);
  bf16_t* W1lt   = (bf16_t*)alloc((size_t)IN_C  * HID_C * 2);
  bf16_t* W1rt   = (bf16_t*)alloc((size_t)IN_C  * HID_C * 2);
  bf16_t* W2lt   = (bf16_t*)alloc((size_t)HID_C * HID_C * 2);
  bf16_t* W2rt   = (bf16_t*)alloc((size_t)HID_C * HID_C * 2);
  bf16_t* Wc3t   = (bf16_t*)alloc((size_t)128 * HID_C * 2);  // [128][256] concat

  // P/Q reuse buffers that are dead by layer 3
  bf16_t* P = aggb;               // [N,64] bf16 (12.8 MB <= 51.2 MB)
  float*  Q = (float*)h1;         // [N,64] f32  (25.6 MB <= 51.2 MB)

  hipMemsetAsync(deg, 0, (size_t)NN * 2 * 4, stream);

  int eb = (EE + 255) / 256;
  int nb = (NN + 255) / 256;

  // conversions
  f2b_vec_k<<<(NN * IN_C / 4 + 255) / 256, 256, 0, stream>>>(x, xb, NN * IN_C);
  WtArgs wa;
  wa.W[0] = W1l; wa.Wt[0] = W1lt; wa.K[0] = IN_C;  wa.N[0] = HID_C;
  wa.W[1] = W1r; wa.Wt[1] = W1rt; wa.K[1] = IN_C;  wa.N[1] = HID_C;
  wa.W[2] = W2l; wa.Wt[2] = W2lt; wa.K[2] = HID_C; wa.N[2] = HID_C;
  wa.W[3] = W2r; wa.Wt[3] = W2rt; wa.K[3] = HID_C; wa.N[3] = HID_C;
  wa.W[4] = Wcl; wa.Wt[4] = Wc3t;             wa.K[4] = HID_C; wa.N[4] = OUT_C;
  wa.W[5] = Wcr; wa.Wt[5] = Wc3t + 64 * 256;  wa.K[5] = HID_C; wa.N[5] = OUT_C;
  wa.off[0] = 0;
  for (int s = 0; s < 6; ++s) wa.off[s + 1] = wa.off[s] + wa.K[s] * wa.N[s];
  wt_all_k<<<(wa.off[6] + 255) / 256, 256, 0, stream>>>(wa);

  // CSR
  detect_edge_k<<<1, 256, 0, stream>>>(ei, eflag);
  count_deg_k<<<eb, 256, 0, stream>>>(ei, eflag, deg);
  scan1_k<<<nb, 256, 0, stream>>>(deg, rowptr, bsums);
  scan2_k<<<1, 512, 0, stream>>>(bsums, nb);
  scan3_k<<<nb, 256, 0, stream>>>(rowptr, bsums);
  fill_k<<<eb, 256, 0, stream>>>(ei, eflag, rowptr, fil, csr);

  int aggblocks = (NN + 3) / 4;
  int mblocks   = (NN + 127) / 128;

  // layer 1: agg over xb [N,128], dual GEMM -> h1 [N,256] bf16, BN+ReLU
  agg_mean_k<IN_C><<<aggblocks, 256, 0, stream>>>(xb, rowptr, csr, aggb);
  dim3 g1d(mblocks, HID_C / 128);
  mfma_gemm_k<128, 4><<<g1d, 256, 0, stream>>>(
      aggb, xb, W1lt, W1rt, b1l, g1, be1, rm1, rv1, h1, NN, IN_C, HID_C);

  // layer 2: agg over h1 [N,256], dual GEMM -> h2 [N,256] bf16, BN+ReLU
  agg_mean_k<HID_C><<<aggblocks, 256, 0, stream>>>(h1, rowptr, csr, aggb);
  mfma_gemm_k<128, 4><<<g1d, 256, 0, stream>>>(
      aggb, h1, W2lt, W2rt, b2l, g2, be2, rm2, rv2, h2, NN, HID_C, HID_C);

  // layer 3 (reordered by linearity of mean-agg):
  //   P = h2@Wcl (bf16), Q = h2@Wcr + bcl (f32); out = mean_agg(P) + Q
  gemm3_k<<<mblocks, 256, 0, stream>>>(h2, Wc3t, bcl, P, Q, NN);
  agg_final_k<<<aggblocks, 256, 0, stream>>>(P, Q, rowptr, csr, (float*)d_out);
}

// Round 5
// 738.450 us; speedup vs baseline: 3.1313x; 1.0692x over previous
//
#include <hip/hip_runtime.h>
#include <stdint.h>

#define NN 100000
#define EE 1600000
#define IN_C 128
#define HID_C 256
#define OUT_C 64

typedef unsigned short bf16_t;
typedef unsigned int u32;
typedef __attribute__((ext_vector_type(8))) short bf16x8;
typedef __attribute__((ext_vector_type(4))) float f32x4;

__device__ __forceinline__ float b2f(unsigned short u){
  unsigned int x = ((unsigned int)u) << 16;
  return __uint_as_float(x);
}
__device__ __forceinline__ unsigned short f2b(float f){
  unsigned int x = __float_as_uint(f);
  unsigned int r = x + 0x7FFFu + ((x >> 16) & 1u);   // RNE
  return (unsigned short)(r >> 16);
}

// ---------------- edge dtype detector ----------------
__global__ void detect_edge_k(const int* __restrict__ ei, int* __restrict__ eflag){
  __shared__ int sm[256];
  int t = threadIdx.x;
  int o = 0;
  for (int i = t; i < 1024; i += 256) o |= ei[2*i + 1];
  sm[t] = o; __syncthreads();
  for (int s = 128; s > 0; s >>= 1){
    if (t < s) sm[t] |= sm[t + s];
    __syncthreads();
  }
  if (t == 0) *eflag = (sm[0] == 0) ? 1 : 0;   // 1 = int64 layout
}

// ---------------- CSR build ----------------

__global__ void count_deg_k(const int* __restrict__ ei, const int* __restrict__ eflag,
                            int* __restrict__ deg){
  int g = blockIdx.x * blockDim.x + threadIdx.x;
  if (g < EE){
    int i64 = *eflag;
    int d = i64 ? ei[2*(EE + g)] : ei[EE + g];
    atomicAdd(&deg[d], 1);
  }
}

__global__ void scan1_k(const int* __restrict__ deg, int* __restrict__ rowptr,
                        int* __restrict__ bsums){
  __shared__ int sm[256];
  int t = threadIdx.x;
  int g = blockIdx.x * 256 + t;
  int v = (g < NN) ? deg[g] : 0;
  sm[t] = v; __syncthreads();
  for (int off = 1; off < 256; off <<= 1){
    int add = (t >= off) ? sm[t - off] : 0;
    __syncthreads();
    sm[t] += add;
    __syncthreads();
  }
  if (g < NN) rowptr[g + 1] = sm[t];
  if (t == 255) bsums[blockIdx.x] = sm[255];
}

__global__ void scan2_k(int* __restrict__ bsums, int nb){
  __shared__ int sm[512];
  int t = threadIdx.x;
  sm[t] = (t < nb) ? bsums[t] : 0; __syncthreads();
  for (int off = 1; off < 512; off <<= 1){
    int add = (t >= off) ? sm[t - off] : 0;
    __syncthreads();
    sm[t] += add;
    __syncthreads();
  }
  if (t < nb) bsums[t] = sm[t];
}

__global__ void scan3_k(int* __restrict__ rowptr, const int* __restrict__ bsums){
  int g = blockIdx.x * 256 + threadIdx.x;
  if (g < NN && blockIdx.x > 0) rowptr[g + 1] += bsums[blockIdx.x - 1];
  if (g == 0) rowptr[0] = 0;
}

__global__ void fill_k(const int* __restrict__ ei, const int* __restrict__ eflag,
                       const int* __restrict__ rowptr, int* __restrict__ fill,
                       int* __restrict__ csr){
  int g = blockIdx.x * blockDim.x + threadIdx.x;
  if (g < EE){
    int i64 = *eflag;
    int s = i64 ? ei[2*g]          : ei[g];
    int d = i64 ? ei[2*(EE + g)]   : ei[EE + g];
    int pos = rowptr[d] + atomicAdd(&fill[d], 1);
    csr[pos] = s;
  }
}

// ---------------- dtype conversion ----------------

__global__ void f2b_vec_k(const float* __restrict__ in, bf16_t* __restrict__ out, int n){
  int g = blockIdx.x * 256 + threadIdx.x;
  int i = g * 4;
  if (i < n){
    float4 v = *(const float4*)(in + i);
    uint2 u;
    u.x = (u32)f2b(v.x) | ((u32)f2b(v.y) << 16);
    u.y = (u32)f2b(v.z) | ((u32)f2b(v.w) << 16);
    *(uint2*)(out + i) = u;
  }
}

struct WtArgs {
  const float* W[6];
  bf16_t* Wt[6];
  int K[6], N[6];
  int off[7];
};

__global__ void wt_all_k(WtArgs a){
  int g = blockIdx.x * 256 + threadIdx.x;
  if (g >= a.off[6]) return;
  #pragma unroll
  for (int s = 0; s < 6; ++s){
    if (g >= a.off[s] && g < a.off[s + 1]){
      int local = g - a.off[s];
      int K = a.K[s], N = a.N[s];
      int n = local / K, k = local - n * K;
      a.Wt[s][local] = f2b(a.W[s][(size_t)k * N + n]);
    }
  }
}

// ---------------- mean aggregation: one wave per node, 8-edge unroll ----------------

template<int C>
__global__ __launch_bounds__(256) void agg_mean_k(const bf16_t* __restrict__ h,
    const int* __restrict__ rowptr, const int* __restrict__ csr,
    bf16_t* __restrict__ outm){
  constexpr int VEC = C / 64;                 // 2 (C=128) or 4 (C=256)
  int wid  = (blockIdx.x * 256 + threadIdx.x) >> 6;
  int lane = threadIdx.x & 63;
  if (wid >= NN) return;
  int beg = __builtin_amdgcn_readfirstlane(rowptr[wid]);
  int end = __builtin_amdgcn_readfirstlane(rowptr[wid + 1]);
  float acc[VEC];
  #pragma unroll
  for (int v = 0; v < VEC; ++v) acc[v] = 0.f;

  int e = beg;
  if constexpr (VEC == 2){
    const bf16_t* hb = h + lane * 2;
    for (; e + 7 < end; e += 8){
      u32 u[8];
      #pragma unroll
      for (int q = 0; q < 8; ++q)
        u[q] = *(const u32*)(hb + (size_t)csr[e + q] * C);
      #pragma unroll
      for (int q = 0; q < 8; ++q){
        acc[0] += b2f((unsigned short)(u[q] & 0xffffu));
        acc[1] += b2f((unsigned short)(u[q] >> 16));
      }
    }
    for (; e < end; ++e){
      u32 u0 = *(const u32*)(hb + (size_t)csr[e] * C);
      acc[0] += b2f((unsigned short)(u0 & 0xffffu));
      acc[1] += b2f((unsigned short)(u0 >> 16));
    }
  } else {
    const bf16_t* hb = h + lane * 4;
    for (; e + 7 < end; e += 8){
      uint2 u[8];
      #pragma unroll
      for (int q = 0; q < 8; ++q)
        u[q] = *(const uint2*)(hb + (size_t)csr[e + q] * C);
      #pragma unroll
      for (int q = 0; q < 8; ++q){
        acc[0] += b2f((unsigned short)(u[q].x & 0xffffu));
        acc[1] += b2f((unsigned short)(u[q].x >> 16));
        acc[2] += b2f((unsigned short)(u[q].y & 0xffffu));
        acc[3] += b2f((unsigned short)(u[q].y >> 16));
      }
    }
    for (; e < end; ++e){
      uint2 u0 = *(const uint2*)(hb + (size_t)csr[e] * C);
      acc[0] += b2f((unsigned short)(u0.x & 0xffffu));
      acc[1] += b2f((unsigned short)(u0.x >> 16));
      acc[2] += b2f((unsigned short)(u0.y & 0xffffu));
      acc[3] += b2f((unsigned short)(u0.y >> 16));
    }
  }

  int d = end - beg;
  float di = d > 0 ? 1.0f / (float)d : 0.f;
  bf16_t* po = outm + (size_t)wid * C + lane * VEC;
  if constexpr (VEC == 2){
    u32 u = (u32)f2b(acc[0] * di) | ((u32)f2b(acc[1] * di) << 16);
    *(u32*)po = u;
  } else {
    uint2 u;
    u.x = (u32)f2b(acc[0] * di) | ((u32)f2b(acc[1] * di) << 16);
    u.y = (u32)f2b(acc[2] * di) | ((u32)f2b(acc[3] * di) << 16);
    *(uint2*)po = u;
  }
}

// ---------------- final aggregation (layer 3, C=64) ----------------

__global__ __launch_bounds__(256) void agg_final_k(
    const bf16_t* __restrict__ P, const float* __restrict__ Q,
    const int* __restrict__ rowptr, const int* __restrict__ csr,
    float* __restrict__ out){
  int wid  = (blockIdx.x * 256 + threadIdx.x) >> 6;
  int lane = threadIdx.x & 63;
  if (wid >= NN) return;
  int beg = __builtin_amdgcn_readfirstlane(rowptr[wid]);
  int end = __builtin_amdgcn_readfirstlane(rowptr[wid + 1]);
  const bf16_t* Pb = P + lane;
  float acc = 0.f;
  int e = beg;
  for (; e + 7 < end; e += 8){
    float a[8];
    #pragma unroll
    for (int q = 0; q < 8; ++q)
      a[q] = b2f(Pb[(size_t)csr[e + q] * 64]);
    #pragma unroll
    for (int q = 0; q < 8; ++q) acc += a[q];
  }
  for (; e < end; ++e) acc += b2f(Pb[(size_t)csr[e] * 64]);
  int d = end - beg;
  float di = d > 0 ? 1.0f / (float)d : 0.f;
  out[(size_t)wid * 64 + lane] = acc * di + Q[(size_t)wid * 64 + lane];
}

// ---------------- MFMA dual-GEMM + bias + BN + ReLU (layers 1,2) ----------------
// BK=64: half the barrier count of BK=32; LDA=72 keeps row stride at 4-bank
// shift -> max 2-way LDS aliasing (free per m136).

template<int BN, int NT_N>
__global__ __launch_bounds__(256) void mfma_gemm_k(
    const bf16_t* __restrict__ A0, const bf16_t* __restrict__ A1,
    const bf16_t* __restrict__ W0t, const bf16_t* __restrict__ W1t,
    const float* __restrict__ bias,
    const float* __restrict__ gamma, const float* __restrict__ beta,
    const float* __restrict__ rmean, const float* __restrict__ rvar,
    bf16_t* __restrict__ out, int M, int K, int Nout)
{
  constexpr int BM = 128;
  constexpr int BK = 64;
  constexpr int LDA = BK + 8;
  __shared__ bf16_t As[BM * LDA];
  __shared__ bf16_t Bs[BN * LDA];

  int t    = threadIdx.x;
  int lane = t & 63;
  int wid  = t >> 6;
  int wr   = wid >> 1, wc = wid & 1;
  int l15  = lane & 15;
  int quad = lane >> 4;

  int m0 = blockIdx.x * BM;
  int n0 = blockIdx.y * BN;

  f32x4 acc[4][NT_N];
  #pragma unroll
  for (int i = 0; i < 4; ++i)
    #pragma unroll
    for (int j = 0; j < NT_N; ++j)
      acc[i][j] = (f32x4){0.f, 0.f, 0.f, 0.f};

  for (int pass = 0; pass < 2; ++pass){
    const bf16_t* A  = pass ? A1 : A0;
    const bf16_t* Wt = pass ? W1t : W0t;
    for (int k0 = 0; k0 < K; k0 += BK){
      #pragma unroll
      for (int i = 0; i < (BM * (BK/8)) / 256; ++i){
        int c = t + i * 256;
        int row = c >> 3, k8 = c & 7;
        uint4 v = make_uint4(0u, 0u, 0u, 0u);
        int gm = m0 + row;
        if (gm < M) v = *(const uint4*)(A + (size_t)gm * K + k0 + k8 * 8);
        *(uint4*)(As + row * LDA + k8 * 8) = v;
      }
      #pragma unroll
      for (int i = 0; i < (BN * (BK/8)) / 256; ++i){
        int c = t + i * 256;
        int row = c >> 3, k8 = c & 7;
        uint4 v = *(const uint4*)(Wt + (size_t)(n0 + row) * K + k0 + k8 * 8);
        *(uint4*)(Bs + row * LDA + k8 * 8) = v;
      }
      __syncthreads();
      #pragma unroll
      for (int kk = 0; kk < BK; kk += 32){
        bf16x8 af[4], bfr[NT_N];
        #pragma unroll
        for (int i = 0; i < 4; ++i)
          af[i] = *(const bf16x8*)(As + (wr * 64 + i * 16 + l15) * LDA + kk + quad * 8);
        #pragma unroll
        for (int j = 0; j < NT_N; ++j)
          bfr[j] = *(const bf16x8*)(Bs + (wc * (NT_N * 16) + j * 16 + l15) * LDA + kk + quad * 8);
        #pragma unroll
        for (int i = 0; i < 4; ++i)
          #pragma unroll
          for (int j = 0; j < NT_N; ++j)
            acc[i][j] = __builtin_amdgcn_mfma_f32_16x16x32_bf16(af[i], bfr[j], acc[i][j], 0, 0, 0);
      }
      __syncthreads();
    }
  }

  #pragma unroll
  for (int j = 0; j < NT_N; ++j){
    int col = n0 + wc * (NT_N * 16) + j * 16 + l15;
    float sc = gamma[col] * rsqrtf(rvar[col] + 1e-5f);
    float shift = (bias[col] - rmean[col]) * sc + beta[col];
    #pragma unroll
    for (int i = 0; i < 4; ++i){
      int rbase = m0 + wr * 64 + i * 16 + quad * 4;
      #pragma unroll
      for (int r = 0; r < 4; ++r){
        int row = rbase + r;
        if (row < M){
          float v = fmaxf(acc[i][j][r] * sc + shift, 0.f);
          out[(size_t)row * Nout + col] = f2b(v);
        }
      }
    }
  }
}

// ---------------- layer-3 single-A GEMM: P = A@Wcl (bf16), Q = A@Wcr + bcl (f32) ----------------

__global__ __launch_bounds__(256) void gemm3_k(
    const bf16_t* __restrict__ A, const bf16_t* __restrict__ Wt,
    const float* __restrict__ bcl,
    bf16_t* __restrict__ P, float* __restrict__ Q, int M)
{
  constexpr int BM = 128, BN = 128, BK = 64, K = 256;
  constexpr int LDA = BK + 8;
  __shared__ bf16_t As[BM * LDA];
  __shared__ bf16_t Bs[BN * LDA];

  int t    = threadIdx.x;
  int lane = t & 63;
  int wid  = t >> 6;
  int wr   = wid >> 1, wc = wid & 1;
  int l15  = lane & 15;
  int quad = lane >> 4;
  int m0 = blockIdx.x * BM;

  f32x4 acc[4][4];
  #pragma unroll
  for (int i = 0; i < 4; ++i)
    #pragma unroll
    for (int j = 0; j < 4; ++j)
      acc[i][j] = (f32x4){0.f, 0.f, 0.f, 0.f};

  for (int k0 = 0; k0 < K; k0 += BK){
    #pragma unroll
    for (int i = 0; i < 4; ++i){
      int c = t + i * 256;
      int row = c >> 3, k8 = c & 7;
      uint4 v = make_uint4(0u, 0u, 0u, 0u);
      int gm = m0 + row;
      if (gm < M) v = *(const uint4*)(A + (size_t)gm * K + k0 + k8 * 8);
      *(uint4*)(As + row * LDA + k8 * 8) = v;
    }
    #pragma unroll
    for (int i = 0; i < 4; ++i){
      int c = t + i * 256;
      int row = c >> 3, k8 = c & 7;
      uint4 v = *(const uint4*)(Wt + (size_t)row * K + k0 + k8 * 8);
      *(uint4*)(Bs + row * LDA + k8 * 8) = v;
    }
    __syncthreads();
    #pragma unroll
    for (int kk = 0; kk < BK; kk += 32){
      bf16x8 af[4], bfr[4];
      #pragma unroll
      for (int i = 0; i < 4; ++i)
        af[i] = *(const bf16x8*)(As + (wr * 64 + i * 16 + l15) * LDA + kk + quad * 8);
      #pragma unroll
      for (int j = 0; j < 4; ++j)
        bfr[j] = *(const bf16x8*)(Bs + (wc * 64 + j * 16 + l15) * LDA + kk + quad * 8);
      #pragma unroll
      for (int i = 0; i < 4; ++i)
        #pragma unroll
        for (int j = 0; j < 4; ++j)
          acc[i][j] = __builtin_amdgcn_mfma_f32_16x16x32_bf16(af[i], bfr[j], acc[i][j], 0, 0, 0);
    }
    __syncthreads();
  }

  #pragma unroll
  for (int j = 0; j < 4; ++j){
    int col = wc * 64 + j * 16 + l15;      // 0..127
    #pragma unroll
    for (int i = 0; i < 4; ++i){
      int rbase = m0 + wr * 64 + i * 16 + quad * 4;
      #pragma unroll
      for (int r = 0; r < 4; ++r){
        int row = rbase + r;
        if (row < M){
          float v = acc[i][j][r];
          if (col < 64) P[(size_t)row * 64 + col] = f2b(v);
          else          Q[(size_t)row * 64 + (col - 64)] = v + bcl[col - 64];
        }
      }
    }
  }
}

// ---------------- launch ----------------

extern "C" void kernel_launch(void* const* d_in, const int* in_sizes, int n_in,
                              void* d_out, int out_size, void* d_ws, size_t ws_size,
                              hipStream_t stream)
{
  const float* x   = (const float*)d_in[0];
  const int*   ei  = (const int*)d_in[1];
  const float* W1l = (const float*)d_in[2];
  const float* b1l = (const float*)d_in[3];
  const float* W1r = (const float*)d_in[4];
  const float* g1  = (const float*)d_in[5];
  const float* be1 = (const float*)d_in[6];
  const float* rm1 = (const float*)d_in[7];
  const float* rv1 = (const float*)d_in[8];
  const float* W2l = (const float*)d_in[9];
  const float* b2l = (const float*)d_in[10];
  const float* W2r = (const float*)d_in[11];
  const float* g2  = (const float*)d_in[12];
  const float* be2 = (const float*)d_in[13];
  const float* rm2 = (const float*)d_in[14];
  const float* rv2 = (const float*)d_in[15];
  const float* Wcl = (const float*)d_in[16];
  const float* bcl = (const float*)d_in[17];
  const float* Wcr = (const float*)d_in[18];
  (void)in_sizes; (void)n_in; (void)out_size; (void)ws_size;

  char* ws = (char*)d_ws;
  size_t off = 0;
  auto alloc = [&](size_t bytes)->char* {
    char* p = ws + off;
    off += (bytes + 15) & ~(size_t)15;
    return p;
  };
  int*    deg    = (int*)   alloc((size_t)NN * 4);
  int*    fil    = (int*)   alloc((size_t)NN * 4);      // contiguous after deg
  int*    rowptr = (int*)   alloc((size_t)(NN + 1) * 4);
  int*    bsums  = (int*)   alloc(512 * 4);
  int*    eflag  = (int*)   alloc(16);
  int*    csr    = (int*)   alloc((size_t)EE * 4);
  bf16_t* xb     = (bf16_t*)alloc((size_t)NN * IN_C * 2);
  bf16_t* aggb   = (bf16_t*)alloc((size_t)NN * HID_C * 2);
  bf16_t* h1     = (bf16_t*)alloc((size_t)NN * HID_C * 2);
  bf16_t* h2     = (bf16_t*)alloc((size_t)NN * HID_C * 2);
  bf16_t* W1lt   = (bf16_t*)alloc((size_t)IN_C  * HID_C * 2);
  bf16_t* W1rt   = (bf16_t*)alloc((size_t)IN_C  * HID_C * 2);
  bf16_t* W2lt   = (bf16_t*)alloc((size_t)HID_C * HID_C * 2);
  bf16_t* W2rt   = (bf16_t*)alloc((size_t)HID_C * HID_C * 2);
  bf16_t* Wc3t   = (bf16_t*)alloc((size_t)128 * HID_C * 2);  // [128][256] concat

  bf16_t* P = aggb;               // [N,64] bf16
  float*  Q = (float*)h1;         // [N,64] f32

  hipMemsetAsync(deg, 0, (size_t)NN * 2 * 4, stream);

  int eb = (EE + 255) / 256;
  int nb = (NN + 255) / 256;

  f2b_vec_k<<<(NN * IN_C / 4 + 255) / 256, 256, 0, stream>>>(x, xb, NN * IN_C);
  WtArgs wa;
  wa.W[0] = W1l; wa.Wt[0] = W1lt; wa.K[0] = IN_C;  wa.N[0] = HID_C;
  wa.W[1] = W1r; wa.Wt[1] = W1rt; wa.K[1] = IN_C;  wa.N[1] = HID_C;
  wa.W[2] = W2l; wa.Wt[2] = W2lt; wa.K[2] = HID_C; wa.N[2] = HID_C;
  wa.W[3] = W2r; wa.Wt[3] = W2rt; wa.K[3] = HID_C; wa.N[3] = HID_C;
  wa.W[4] = Wcl; wa.Wt[4] = Wc3t;             wa.K[4] = HID_C; wa.N[4] = OUT_C;
  wa.W[5] = Wcr; wa.Wt[5] = Wc3t + 64 * 256;  wa.K[5] = HID_C; wa.N[5] = OUT_C;
  wa.off[0] = 0;
  for (int s = 0; s < 6; ++s) wa.off[s + 1] = wa.off[s] + wa.K[s] * wa.N[s];
  wt_all_k<<<(wa.off[6] + 255) / 256, 256, 0, stream>>>(wa);

  detect_edge_k<<<1, 256, 0, stream>>>(ei, eflag);
  count_deg_k<<<eb, 256, 0, stream>>>(ei, eflag, deg);
  scan1_k<<<nb, 256, 0, stream>>>(deg, rowptr, bsums);
  scan2_k<<<1, 512, 0, stream>>>(bsums, nb);
  scan3_k<<<nb, 256, 0, stream>>>(rowptr, bsums);
  fill_k<<<eb, 256, 0, stream>>>(ei, eflag, rowptr, fil, csr);

  int aggblocks = (NN + 3) / 4;
  int mblocks   = (NN + 127) / 128;

  // layer 1
  agg_mean_k<IN_C><<<aggblocks, 256, 0, stream>>>(xb, rowptr, csr, aggb);
  dim3 g1d(mblocks, HID_C / 128);
  mfma_gemm_k<128, 4><<<g1d, 256, 0, stream>>>(
      aggb, xb, W1lt, W1rt, b1l, g1, be1, rm1, rv1, h1, NN, IN_C, HID_C);

  // layer 2
  agg_mean_k<HID_C><<<aggblocks, 256, 0, stream>>>(h1, rowptr, csr, aggb);
  mfma_gemm_k<128, 4><<<g1d, 256, 0, stream>>>(
      aggb, h1, W2lt, W2rt, b2l, g2, be2, rm2, rv2, h2, NN, HID_C, HID_C);

  // layer 3 (linearity-reordered)
  gemm3_k<<<mblocks, 256, 0, stream>>>(h2, Wc3t, bcl, P, Q, NN);
  agg_final_k<<<aggblocks, 256, 0, stream>>>(P, Q, rowptr, csr, (float*)d_out);
}

// Round 6
// 718.470 us; speedup vs baseline: 3.2183x; 1.0278x over previous
//
#include <hip/hip_runtime.h>
#include <stdint.h>

#define NN 100000
#define EE 1600000
#define IN_C 128
#define HID_C 256
#define OUT_C 64

typedef unsigned short bf16_t;
typedef unsigned int u32;
typedef __attribute__((ext_vector_type(8))) short bf16x8;
typedef __attribute__((ext_vector_type(4))) float f32x4;

__device__ __forceinline__ float b2f(unsigned short u){
  unsigned int x = ((unsigned int)u) << 16;
  return __uint_as_float(x);
}
__device__ __forceinline__ unsigned short f2b(float f){
  unsigned int x = __float_as_uint(f);
  unsigned int r = x + 0x7FFFu + ((x >> 16) & 1u);   // RNE
  return (unsigned short)(r >> 16);
}

// ---------------- edge dtype detector ----------------
__global__ void detect_edge_k(const int* __restrict__ ei, int* __restrict__ eflag){
  __shared__ int sm[256];
  int t = threadIdx.x;
  int o = 0;
  for (int i = t; i < 1024; i += 256) o |= ei[2*i + 1];
  sm[t] = o; __syncthreads();
  for (int s = 128; s > 0; s >>= 1){
    if (t < s) sm[t] |= sm[t + s];
    __syncthreads();
  }
  if (t == 0) *eflag = (sm[0] == 0) ? 1 : 0;   // 1 = int64 layout
}

// ---------------- CSR build ----------------

__global__ void count_deg_k(const int* __restrict__ ei, const int* __restrict__ eflag,
                            int* __restrict__ deg){
  int g = blockIdx.x * blockDim.x + threadIdx.x;
  if (g < EE){
    int i64 = *eflag;
    int d = i64 ? ei[2*(EE + g)] : ei[EE + g];
    atomicAdd(&deg[d], 1);
  }
}

__global__ void scan1_k(const int* __restrict__ deg, int* __restrict__ rowptr,
                        int* __restrict__ bsums){
  __shared__ int sm[256];
  int t = threadIdx.x;
  int g = blockIdx.x * 256 + t;
  int v = (g < NN) ? deg[g] : 0;
  sm[t] = v; __syncthreads();
  for (int off = 1; off < 256; off <<= 1){
    int add = (t >= off) ? sm[t - off] : 0;
    __syncthreads();
    sm[t] += add;
    __syncthreads();
  }
  if (g < NN) rowptr[g + 1] = sm[t];
  if (t == 255) bsums[blockIdx.x] = sm[255];
}

__global__ void scan2_k(int* __restrict__ bsums, int nb){
  __shared__ int sm[512];
  int t = threadIdx.x;
  sm[t] = (t < nb) ? bsums[t] : 0; __syncthreads();
  for (int off = 1; off < 512; off <<= 1){
    int add = (t >= off) ? sm[t - off] : 0;
    __syncthreads();
    sm[t] += add;
    __syncthreads();
  }
  if (t < nb) bsums[t] = sm[t];
}

__global__ void scan3_k(int* __restrict__ rowptr, const int* __restrict__ bsums){
  int g = blockIdx.x * 256 + threadIdx.x;
  if (g < NN && blockIdx.x > 0) rowptr[g + 1] += bsums[blockIdx.x - 1];
  if (g == 0) rowptr[0] = 0;
}

__global__ void fill_k(const int* __restrict__ ei, const int* __restrict__ eflag,
                       const int* __restrict__ rowptr, int* __restrict__ fill,
                       int* __restrict__ csr){
  int g = blockIdx.x * blockDim.x + threadIdx.x;
  if (g < EE){
    int i64 = *eflag;
    int s = i64 ? ei[2*g]          : ei[g];
    int d = i64 ? ei[2*(EE + g)]   : ei[EE + g];
    int pos = rowptr[d] + atomicAdd(&fill[d], 1);
    csr[pos] = s;
  }
}

// ---------------- dtype conversion ----------------

__global__ void f2b_vec_k(const float* __restrict__ in, bf16_t* __restrict__ out, int n){
  int g = blockIdx.x * 256 + threadIdx.x;
  int i = g * 4;
  if (i < n){
    float4 v = *(const float4*)(in + i);
    uint2 u;
    u.x = (u32)f2b(v.x) | ((u32)f2b(v.y) << 16);
    u.y = (u32)f2b(v.z) | ((u32)f2b(v.w) << 16);
    *(uint2*)(out + i) = u;
  }
}

struct WtArgs {
  const float* W[6];
  bf16_t* Wt[6];
  int K[6], N[6];
  int off[7];
};

__global__ void wt_all_k(WtArgs a){
  int g = blockIdx.x * 256 + threadIdx.x;
  if (g >= a.off[6]) return;
  #pragma unroll
  for (int s = 0; s < 6; ++s){
    if (g >= a.off[s] && g < a.off[s + 1]){
      int local = g - a.off[s];
      int K = a.K[s], N = a.N[s];
      int n = local / K, k = local - n * K;
      a.Wt[s][local] = f2b(a.W[s][(size_t)k * N + n]);
    }
  }
}

// ---------------- per-row quantization: one wave per row ----------------
// SIGNED: int8 symmetric (max|v|/127). !SIGNED: uint8 (values >= 0, max/255).
// TIN = float or bf16_t.

template<int C, bool SIGNED, typename TIN>
__global__ __launch_bounds__(256) void quant_k(const TIN* __restrict__ in,
    uint8_t* __restrict__ outq, float* __restrict__ scales){
  constexpr int V = C / 64;      // elems per lane: 4 / 2 / 1
  int row  = (blockIdx.x * 256 + threadIdx.x) >> 6;
  int lane = threadIdx.x & 63;
  if (row >= NN) return;
  float v[V];
  if constexpr (sizeof(TIN) == 4){
    // float input (only V==2 used: C=128)
    float2 u = *(const float2*)((const float*)in + (size_t)row * C + lane * 2);
    v[0] = u.x; v[1] = u.y;
  } else {
    const bf16_t* bp = (const bf16_t*)in + (size_t)row * C + lane * V;
    if constexpr (V == 4){
      uint2 u = *(const uint2*)bp;
      v[0] = b2f((unsigned short)(u.x & 0xffffu)); v[1] = b2f((unsigned short)(u.x >> 16));
      v[2] = b2f((unsigned short)(u.y & 0xffffu)); v[3] = b2f((unsigned short)(u.y >> 16));
    } else if constexpr (V == 2){
      u32 u = *(const u32*)bp;
      v[0] = b2f((unsigned short)(u & 0xffffu)); v[1] = b2f((unsigned short)(u >> 16));
    } else {
      v[0] = b2f(*bp);
    }
  }
  float m = 0.f;
  #pragma unroll
  for (int i = 0; i < V; ++i) m = fmaxf(m, SIGNED ? fabsf(v[i]) : v[i]);
  #pragma unroll
  for (int msk = 1; msk < 64; msk <<= 1) m = fmaxf(m, __shfl_xor(m, msk, 64));
  const float qmax = SIGNED ? 127.f : 255.f;
  float inv = m > 0.f ? qmax / m : 0.f;
  uint8_t qb[V];
  #pragma unroll
  for (int i = 0; i < V; ++i){
    float qf = rintf(v[i] * inv);
    if (SIGNED){
      qf = fminf(fmaxf(qf, -127.f), 127.f);
      qb[i] = (uint8_t)(int8_t)(int)qf;
    } else {
      qf = fminf(fmaxf(qf, 0.f), 255.f);
      qb[i] = (uint8_t)(int)qf;
    }
  }
  uint8_t* op = outq + (size_t)row * C + lane * V;
  if constexpr (V == 4){
    u32 p = (u32)qb[0] | ((u32)qb[1] << 8) | ((u32)qb[2] << 16) | ((u32)qb[3] << 24);
    *(u32*)op = p;
  } else if constexpr (V == 2){
    *(unsigned short*)op = (unsigned short)((u32)qb[0] | ((u32)qb[1] << 8));
  } else {
    *op = qb[0];
  }
  if (lane == 0) scales[row] = m / qmax;
}

// ---------------- mean aggregation over quantized rows ----------------

__device__ __forceinline__ float qdec(u32 w, int b, bool sgn){
  u32 byte = (w >> (8 * b)) & 0xffu;
  return sgn ? (float)(int8_t)byte : (float)byte;
}

template<int C, bool SIGNED>
__global__ __launch_bounds__(256) void agg_q8_k(const uint8_t* __restrict__ tq,
    const float* __restrict__ tsc,
    const int* __restrict__ rowptr, const int* __restrict__ csr,
    bf16_t* __restrict__ outm){
  constexpr int V = C / 64;          // bytes per lane: 4 (C=256) or 2 (C=128)
  int wid  = (blockIdx.x * 256 + threadIdx.x) >> 6;
  int lane = threadIdx.x & 63;
  if (wid >= NN) return;
  int beg = __builtin_amdgcn_readfirstlane(rowptr[wid]);
  int end = __builtin_amdgcn_readfirstlane(rowptr[wid + 1]);
  float acc[V];
  #pragma unroll
  for (int i = 0; i < V; ++i) acc[i] = 0.f;

  const uint8_t* hb = tq + lane * V;
  int e = beg;
  for (; e + 7 < end; e += 8){
    int   s[8]; float sc[8];
    #pragma unroll
    for (int q = 0; q < 8; ++q) s[q] = csr[e + q];
    u32 w[8];
    #pragma unroll
    for (int q = 0; q < 8; ++q){
      if constexpr (V == 4) w[q] = *(const u32*)(hb + (size_t)s[q] * C);
      else                  w[q] = *(const unsigned short*)(hb + (size_t)s[q] * C);
      sc[q] = tsc[s[q]];
    }
    #pragma unroll
    for (int q = 0; q < 8; ++q)
      #pragma unroll
      for (int i = 0; i < V; ++i)
        acc[i] += sc[q] * qdec(w[q], i, SIGNED);
  }
  for (; e < end; ++e){
    int s0 = csr[e];
    u32 w0;
    if constexpr (V == 4) w0 = *(const u32*)(hb + (size_t)s0 * C);
    else                  w0 = *(const unsigned short*)(hb + (size_t)s0 * C);
    float sc0 = tsc[s0];
    #pragma unroll
    for (int i = 0; i < V; ++i) acc[i] += sc0 * qdec(w0, i, SIGNED);
  }

  int d = end - beg;
  float di = d > 0 ? 1.0f / (float)d : 0.f;
  bf16_t* po = outm + (size_t)wid * C + lane * V;
  if constexpr (V == 2){
    u32 u = (u32)f2b(acc[0] * di) | ((u32)f2b(acc[1] * di) << 16);
    *(u32*)po = u;
  } else {
    uint2 u;
    u.x = (u32)f2b(acc[0] * di) | ((u32)f2b(acc[1] * di) << 16);
    u.y = (u32)f2b(acc[2] * di) | ((u32)f2b(acc[3] * di) << 16);
    *(uint2*)po = u;
  }
}

// ---------------- final aggregation (layer 3, C=64, int8 P) ----------------

__global__ __launch_bounds__(256) void agg_final_q8_k(
    const uint8_t* __restrict__ Pq, const float* __restrict__ scp,
    const float* __restrict__ Q,
    const int* __restrict__ rowptr, const int* __restrict__ csr,
    float* __restrict__ out){
  int wid  = (blockIdx.x * 256 + threadIdx.x) >> 6;
  int lane = threadIdx.x & 63;
  if (wid >= NN) return;
  int beg = __builtin_amdgcn_readfirstlane(rowptr[wid]);
  int end = __builtin_amdgcn_readfirstlane(rowptr[wid + 1]);
  const uint8_t* Pb = Pq + lane;
  float acc = 0.f;
  int e = beg;
  for (; e + 7 < end; e += 8){
    int s[8]; uint8_t b[8]; float sc[8];
    #pragma unroll
    for (int q = 0; q < 8; ++q) s[q] = csr[e + q];
    #pragma unroll
    for (int q = 0; q < 8; ++q){ b[q] = Pb[(size_t)s[q] * 64]; sc[q] = scp[s[q]]; }
    #pragma unroll
    for (int q = 0; q < 8; ++q) acc += sc[q] * (float)(int8_t)b[q];
  }
  for (; e < end; ++e) acc += scp[csr[e]] * (float)(int8_t)Pb[(size_t)csr[e] * 64];
  int d = end - beg;
  float di = d > 0 ? 1.0f / (float)d : 0.f;
  out[(size_t)wid * 64 + lane] = acc * di + Q[(size_t)wid * 64 + lane];
}

// ---------------- MFMA dual-GEMM + bias + BN + ReLU (layers 1,2) ----------------

template<int BN, int NT_N>
__global__ __launch_bounds__(256) void mfma_gemm_k(
    const bf16_t* __restrict__ A0, const bf16_t* __restrict__ A1,
    const bf16_t* __restrict__ W0t, const bf16_t* __restrict__ W1t,
    const float* __restrict__ bias,
    const float* __restrict__ gamma, const float* __restrict__ beta,
    const float* __restrict__ rmean, const float* __restrict__ rvar,
    bf16_t* __restrict__ out, int M, int K, int Nout)
{
  constexpr int BM = 128;
  constexpr int BK = 64;
  constexpr int LDA = BK + 8;
  __shared__ bf16_t As[BM * LDA];
  __shared__ bf16_t Bs[BN * LDA];

  int t    = threadIdx.x;
  int lane = t & 63;
  int wid  = t >> 6;
  int wr   = wid >> 1, wc = wid & 1;
  int l15  = lane & 15;
  int quad = lane >> 4;

  int m0 = blockIdx.x * BM;
  int n0 = blockIdx.y * BN;

  f32x4 acc[4][NT_N];
  #pragma unroll
  for (int i = 0; i < 4; ++i)
    #pragma unroll
    for (int j = 0; j < NT_N; ++j)
      acc[i][j] = (f32x4){0.f, 0.f, 0.f, 0.f};

  for (int pass = 0; pass < 2; ++pass){
    const bf16_t* A  = pass ? A1 : A0;
    const bf16_t* Wt = pass ? W1t : W0t;
    for (int k0 = 0; k0 < K; k0 += BK){
      #pragma unroll
      for (int i = 0; i < (BM * (BK/8)) / 256; ++i){
        int c = t + i * 256;
        int row = c >> 3, k8 = c & 7;
        uint4 v = make_uint4(0u, 0u, 0u, 0u);
        int gm = m0 + row;
        if (gm < M) v = *(const uint4*)(A + (size_t)gm * K + k0 + k8 * 8);
        *(uint4*)(As + row * LDA + k8 * 8) = v;
      }
      #pragma unroll
      for (int i = 0; i < (BN * (BK/8)) / 256; ++i){
        int c = t + i * 256;
        int row = c >> 3, k8 = c & 7;
        uint4 v = *(const uint4*)(Wt + (size_t)(n0 + row) * K + k0 + k8 * 8);
        *(uint4*)(Bs + row * LDA + k8 * 8) = v;
      }
      __syncthreads();
      #pragma unroll
      for (int kk = 0; kk < BK; kk += 32){
        bf16x8 af[4], bfr[NT_N];
        #pragma unroll
        for (int i = 0; i < 4; ++i)
          af[i] = *(const bf16x8*)(As + (wr * 64 + i * 16 + l15) * LDA + kk + quad * 8);
        #pragma unroll
        for (int j = 0; j < NT_N; ++j)
          bfr[j] = *(const bf16x8*)(Bs + (wc * (NT_N * 16) + j * 16 + l15) * LDA + kk + quad * 8);
        #pragma unroll
        for (int i = 0; i < 4; ++i)
          #pragma unroll
          for (int j = 0; j < NT_N; ++j)
            acc[i][j] = __builtin_amdgcn_mfma_f32_16x16x32_bf16(af[i], bfr[j], acc[i][j], 0, 0, 0);
      }
      __syncthreads();
    }
  }

  #pragma unroll
  for (int j = 0; j < NT_N; ++j){
    int col = n0 + wc * (NT_N * 16) + j * 16 + l15;
    float sc = gamma[col] * rsqrtf(rvar[col] + 1e-5f);
    float shift = (bias[col] - rmean[col]) * sc + beta[col];
    #pragma unroll
    for (int i = 0; i < 4; ++i){
      int rbase = m0 + wr * 64 + i * 16 + quad * 4;
      #pragma unroll
      for (int r = 0; r < 4; ++r){
        int row = rbase + r;
        if (row < M){
          float v = fmaxf(acc[i][j][r] * sc + shift, 0.f);
          out[(size_t)row * Nout + col] = f2b(v);
        }
      }
    }
  }
}

// ---------------- layer-3 single-A GEMM: P = A@Wcl (bf16), Q = A@Wcr + bcl (f32) ----------------

__global__ __launch_bounds__(256) void gemm3_k(
    const bf16_t* __restrict__ A, const bf16_t* __restrict__ Wt,
    const float* __restrict__ bcl,
    bf16_t* __restrict__ P, float* __restrict__ Q, int M)
{
  constexpr int BM = 128, BN = 128, BK = 64, K = 256;
  constexpr int LDA = BK + 8;
  __shared__ bf16_t As[BM * LDA];
  __shared__ bf16_t Bs[BN * LDA];

  int t    = threadIdx.x;
  int lane = t & 63;
  int wid  = t >> 6;
  int wr   = wid >> 1, wc = wid & 1;
  int l15  = lane & 15;
  int quad = lane >> 4;
  int m0 = blockIdx.x * BM;

  f32x4 acc[4][4];
  #pragma unroll
  for (int i = 0; i < 4; ++i)
    #pragma unroll
    for (int j = 0; j < 4; ++j)
      acc[i][j] = (f32x4){0.f, 0.f, 0.f, 0.f};

  for (int k0 = 0; k0 < K; k0 += BK){
    #pragma unroll
    for (int i = 0; i < 4; ++i){
      int c = t + i * 256;
      int row = c >> 3, k8 = c & 7;
      uint4 v = make_uint4(0u, 0u, 0u, 0u);
      int gm = m0 + row;
      if (gm < M) v = *(const uint4*)(A + (size_t)gm * K + k0 + k8 * 8);
      *(uint4*)(As + row * LDA + k8 * 8) = v;
    }
    #pragma unroll
    for (int i = 0; i < 4; ++i){
      int c = t + i * 256;
      int row = c >> 3, k8 = c & 7;
      uint4 v = *(const uint4*)(Wt + (size_t)row * K + k0 + k8 * 8);
      *(uint4*)(Bs + row * LDA + k8 * 8) = v;
    }
    __syncthreads();
    #pragma unroll
    for (int kk = 0; kk < BK; kk += 32){
      bf16x8 af[4], bfr[4];
      #pragma unroll
      for (int i = 0; i < 4; ++i)
        af[i] = *(const bf16x8*)(As + (wr * 64 + i * 16 + l15) * LDA + kk + quad * 8);
      #pragma unroll
      for (int j = 0; j < 4; ++j)
        bfr[j] = *(const bf16x8*)(Bs + (wc * 64 + j * 16 + l15) * LDA + kk + quad * 8);
      #pragma unroll
      for (int i = 0; i < 4; ++i)
        #pragma unroll
        for (int j = 0; j < 4; ++j)
          acc[i][j] = __builtin_amdgcn_mfma_f32_16x16x32_bf16(af[i], bfr[j], acc[i][j], 0, 0, 0);
    }
    __syncthreads();
  }

  #pragma unroll
  for (int j = 0; j < 4; ++j){
    int col = wc * 64 + j * 16 + l15;      // 0..127
    #pragma unroll
    for (int i = 0; i < 4; ++i){
      int rbase = m0 + wr * 64 + i * 16 + quad * 4;
      #pragma unroll
      for (int r = 0; r < 4; ++r){
        int row = rbase + r;
        if (row < M){
          float v = acc[i][j][r];
          if (col < 64) P[(size_t)row * 64 + col] = f2b(v);
          else          Q[(size_t)row * 64 + (col - 64)] = v + bcl[col - 64];
        }
      }
    }
  }
}

// ---------------- launch ----------------

extern "C" void kernel_launch(void* const* d_in, const int* in_sizes, int n_in,
                              void* d_out, int out_size, void* d_ws, size_t ws_size,
                              hipStream_t stream)
{
  const float* x   = (const float*)d_in[0];
  const int*   ei  = (const int*)d_in[1];
  const float* W1l = (const float*)d_in[2];
  const float* b1l = (const float*)d_in[3];
  const float* W1r = (const float*)d_in[4];
  const float* g1  = (const float*)d_in[5];
  const float* be1 = (const float*)d_in[6];
  const float* rm1 = (const float*)d_in[7];
  const float* rv1 = (const float*)d_in[8];
  const float* W2l = (const float*)d_in[9];
  const float* b2l = (const float*)d_in[10];
  const float* W2r = (const float*)d_in[11];
  const float* g2  = (const float*)d_in[12];
  const float* be2 = (const float*)d_in[13];
  const float* rm2 = (const float*)d_in[14];
  const float* rv2 = (const float*)d_in[15];
  const float* Wcl = (const float*)d_in[16];
  const float* bcl = (const float*)d_in[17];
  const float* Wcr = (const float*)d_in[18];
  (void)in_sizes; (void)n_in; (void)out_size; (void)ws_size;

  char* ws = (char*)d_ws;
  size_t off = 0;
  auto alloc = [&](size_t bytes)->char* {
    char* p = ws + off;
    off += (bytes + 15) & ~(size_t)15;
    return p;
  };
  int*    deg    = (int*)   alloc((size_t)NN * 4);
  int*    fil    = (int*)   alloc((size_t)NN * 4);      // contiguous after deg
  int*    rowptr = (int*)   alloc((size_t)(NN + 1) * 4);
  int*    bsums  = (int*)   alloc(512 * 4);
  int*    eflag  = (int*)   alloc(16);
  int*    csr    = (int*)   alloc((size_t)EE * 4);
  bf16_t* xb     = (bf16_t*)alloc((size_t)NN * IN_C * 2);
  bf16_t* aggb   = (bf16_t*)alloc((size_t)NN * HID_C * 2);
  bf16_t* h1     = (bf16_t*)alloc((size_t)NN * HID_C * 2);
  bf16_t* h2     = (bf16_t*)alloc((size_t)NN * HID_C * 2);
  bf16_t* W1lt   = (bf16_t*)alloc((size_t)IN_C  * HID_C * 2);
  bf16_t* W1rt   = (bf16_t*)alloc((size_t)IN_C  * HID_C * 2);
  bf16_t* W2lt   = (bf16_t*)alloc((size_t)HID_C * HID_C * 2);
  bf16_t* W2rt   = (bf16_t*)alloc((size_t)HID_C * HID_C * 2);
  bf16_t* Wc3t   = (bf16_t*)alloc((size_t)128 * HID_C * 2);  // [128][256] concat
  float*  sc1    = (float*) alloc((size_t)NN * 4);           // h1 row scales
  float*  scp    = (float*) alloc((size_t)NN * 4);           // P row scales

  // aliases into dead-by-then regions:
  uint8_t* xq  = (uint8_t*)h2;                       // [N,128] s8, dead before GEMM2 writes h2
  float*   scx = (float*)((char*)h2 + (size_t)NN * IN_C);
  uint8_t* h1q = (uint8_t*)xb;                       // [N,256] u8, xb dead after GEMM1
  bf16_t*  P   = xb;                                 // [N,64] bf16, h1q dead after layer-2 agg
  uint8_t* Pq  = (uint8_t*)aggb;                     // [N,64] s8, aggb dead after GEMM2
  float*   Q   = (float*)h1;                         // [N,64] f32, h1 dead after GEMM2

  hipMemsetAsync(deg, 0, (size_t)NN * 2 * 4, stream);

  int eb = (EE + 255) / 256;
  int nb = (NN + 255) / 256;
  int wb = (NN + 3) / 4;        // one wave per row/node kernels

  f2b_vec_k<<<(NN * IN_C / 4 + 255) / 256, 256, 0, stream>>>(x, xb, NN * IN_C);
  WtArgs wa;
  wa.W[0] = W1l; wa.Wt[0] = W1lt; wa.K[0] = IN_C;  wa.N[0] = HID_C;
  wa.W[1] = W1r; wa.Wt[1] = W1rt; wa.K[1] = IN_C;  wa.N[1] = HID_C;
  wa.W[2] = W2l; wa.Wt[2] = W2lt; wa.K[2] = HID_C; wa.N[2] = HID_C;
  wa.W[3] = W2r; wa.Wt[3] = W2rt; wa.K[3] = HID_C; wa.N[3] = HID_C;
  wa.W[4] = Wcl; wa.Wt[4] = Wc3t;             wa.K[4] = HID_C; wa.N[4] = OUT_C;
  wa.W[5] = Wcr; wa.Wt[5] = Wc3t + 64 * 256;  wa.K[5] = HID_C; wa.N[5] = OUT_C;
  wa.off[0] = 0;
  for (int s = 0; s < 6; ++s) wa.off[s + 1] = wa.off[s] + wa.K[s] * wa.N[s];
  wt_all_k<<<(wa.off[6] + 255) / 256, 256, 0, stream>>>(wa);

  detect_edge_k<<<1, 256, 0, stream>>>(ei, eflag);
  count_deg_k<<<eb, 256, 0, stream>>>(ei, eflag, deg);
  scan1_k<<<nb, 256, 0, stream>>>(deg, rowptr, bsums);
  scan2_k<<<1, 512, 0, stream>>>(bsums, nb);
  scan3_k<<<nb, 256, 0, stream>>>(rowptr, bsums);
  fill_k<<<eb, 256, 0, stream>>>(ei, eflag, rowptr, fil, csr);

  int mblocks = (NN + 127) / 128;

  // layer 1: quantize x (s8 per-row), agg, dual GEMM -> h1 (BN+ReLU)
  quant_k<IN_C, true, float><<<wb, 256, 0, stream>>>(x, xq, scx);
  agg_q8_k<IN_C, true><<<wb, 256, 0, stream>>>(xq, scx, rowptr, csr, aggb);
  dim3 g1d(mblocks, HID_C / 128);
  mfma_gemm_k<128, 4><<<g1d, 256, 0, stream>>>(
      aggb, xb, W1lt, W1rt, b1l, g1, be1, rm1, rv1, h1, NN, IN_C, HID_C);

  // layer 2: quantize h1 (u8 per-row, post-ReLU), agg, dual GEMM -> h2 (BN+ReLU)
  quant_k<HID_C, false, bf16_t><<<wb, 256, 0, stream>>>(h1, h1q, sc1);
  agg_q8_k<HID_C, false><<<wb, 256, 0, stream>>>(h1q, sc1, rowptr, csr, aggb);
  mfma_gemm_k<128, 4><<<g1d, 256, 0, stream>>>(
      aggb, h1, W2lt, W2rt, b2l, g2, be2, rm2, rv2, h2, NN, HID_C, HID_C);

  // layer 3 (linearity-reordered): P = h2@Wcl, Q = h2@Wcr + bcl; out = agg(P) + Q
  gemm3_k<<<mblocks, 256, 0, stream>>>(h2, Wc3t, bcl, P, Q, NN);
  quant_k<OUT_C, true, bf16_t><<<wb, 256, 0, stream>>>(P, Pq, scp);
  agg_final_q8_k<<<wb, 256, 0, stream>>>(Pq, scp, Q, rowptr, csr, (float*)d_out);
}

// Round 7
// 610.476 us; speedup vs baseline: 3.7877x; 1.1769x over previous
//
#include <hip/hip_runtime.h>
#include <stdint.h>

#define NN 100000
#define EE 1600000
#define IN_C 128
#define HID_C 256
#define OUT_C 64

#define NB 391            // CSR buckets: 256 node-ids each (391*256 = 100096 >= NN)
#define CAP 5120          // LDS sort capacity per bucket (expected 4096, +16 sigma)
#define K3_NPT 25         // edges per thread in bucket kernels
#define K3_BLOCKS 250     // 250 * 256 * 25 = 1.6M = EE exactly

typedef unsigned short bf16_t;
typedef unsigned int u32;
typedef __attribute__((ext_vector_type(8))) short bf16x8;
typedef __attribute__((ext_vector_type(4))) float f32x4;

__device__ __forceinline__ float b2f(unsigned short u){
  unsigned int x = ((unsigned int)u) << 16;
  return __uint_as_float(x);
}
__device__ __forceinline__ unsigned short f2b(float f){
  unsigned int x = __float_as_uint(f);
  unsigned int r = x + 0x7FFFu + ((x >> 16) & 1u);   // RNE
  return (unsigned short)(r >> 16);
}

// ---------------- edge dtype detector ----------------
__global__ void detect_edge_k(const int* __restrict__ ei, int* __restrict__ eflag){
  __shared__ int sm[256];
  int t = threadIdx.x;
  int o = 0;
  for (int i = t; i < 1024; i += 256) o |= ei[2*i + 1];
  sm[t] = o; __syncthreads();
  for (int s = 128; s > 0; s >>= 1){
    if (t < s) sm[t] |= sm[t + s];
    __syncthreads();
  }
  if (t == 0) *eflag = (sm[0] == 0) ? 1 : 0;   // 1 = int64 layout
}

// ---------------- CSR build: bucketed two-phase sort ----------------
// K1: per-bucket edge counts (LDS histogram, few global atomics)
__global__ __launch_bounds__(256) void bcount_k(const int* __restrict__ ei,
    const int* __restrict__ eflag, int* __restrict__ bcnt){
  __shared__ int h[NB];
  int t = threadIdx.x;
  for (int i = t; i < NB; i += 256) h[i] = 0;
  __syncthreads();
  int i64 = *eflag;
  int base = blockIdx.x * (256 * K3_NPT);
  #pragma unroll
  for (int q = 0; q < K3_NPT; ++q){
    int e = base + q * 256 + t;
    int d = i64 ? ei[2*(EE + e)] : ei[EE + e];
    atomicAdd(&h[d >> 8], 1);
  }
  __syncthreads();
  for (int i = t; i < NB; i += 256) if (h[i]) atomicAdd(&bcnt[i], h[i]);
}

// K2: exclusive scan of bucket counts -> bbase[0..NB]
__global__ void bscan_k(const int* __restrict__ bcnt, int* __restrict__ bbase){
  __shared__ int sm[512];
  int t = threadIdx.x;
  sm[t] = (t < NB) ? bcnt[t] : 0;
  __syncthreads();
  for (int off = 1; off < 512; off <<= 1){
    int a = (t >= off) ? sm[t - off] : 0;
    __syncthreads();
    sm[t] += a;
    __syncthreads();
  }
  if (t <= NB) bbase[t] = (t == 0) ? 0 : sm[t - 1];
}

// K3: scatter (src,dst) into bucket-grouped pairs with per-(block,bucket)
// reservations -> writes are sequential runs (L2 line-merge friendly)
__global__ __launch_bounds__(256) void bscatter_k(const int* __restrict__ ei,
    const int* __restrict__ eflag, const int* __restrict__ bbase,
    int* __restrict__ bfill, uint2* __restrict__ pairs){
  __shared__ int cnt[NB];
  __shared__ int cnt2[NB];
  __shared__ int lbase[NB];
  int t = threadIdx.x;
  for (int i = t; i < NB; i += 256){ cnt[i] = 0; cnt2[i] = 0; }
  __syncthreads();
  int i64 = *eflag;
  int ebase = blockIdx.x * (256 * K3_NPT);
  int src[K3_NPT], dst[K3_NPT];
  #pragma unroll
  for (int q = 0; q < K3_NPT; ++q){
    int e = ebase + q * 256 + t;
    src[q] = i64 ? ei[2*e] : ei[e];
    dst[q] = i64 ? ei[2*(EE + e)] : ei[EE + e];
    atomicAdd(&cnt[dst[q] >> 8], 1);
  }
  __syncthreads();
  for (int i = t; i < NB; i += 256)
    lbase[i] = cnt[i] ? atomicAdd(&bfill[i], cnt[i]) : 0;
  __syncthreads();
  #pragma unroll
  for (int q = 0; q < K3_NPT; ++q){
    int b = dst[q] >> 8;
    int r = atomicAdd(&cnt2[b], 1);
    pairs[bbase[b] + lbase[b] + r] = make_uint2((u32)src[q], (u32)dst[q]);
  }
}

// K4: per-bucket counting sort in LDS -> coalesced csr + rowptr writes
__global__ __launch_bounds__(256) void bsort_k(const uint2* __restrict__ pairs,
    const int* __restrict__ bbase, int* __restrict__ rowptr, int* __restrict__ csr){
  __shared__ int hist[256];
  __shared__ int pref[257];
  __shared__ int cnt[256];
  __shared__ int lsrc[CAP];
  int b = blockIdx.x;
  int t = threadIdx.x;
  int e0 = bbase[b], e1 = bbase[b + 1];
  int s = e1 - e0;
  hist[t] = 0; cnt[t] = 0;
  __syncthreads();
  for (int i = t; i < s; i += 256)
    atomicAdd(&hist[pairs[e0 + i].y & 255], 1);
  __syncthreads();
  // inclusive scan of hist
  for (int off = 1; off < 256; off <<= 1){
    int a = (t >= off) ? hist[t - off] : 0;
    __syncthreads();
    hist[t] += a;
    __syncthreads();
  }
  if (t == 0) pref[0] = 0;
  pref[t + 1] = hist[t];
  __syncthreads();
  // rowptr: global node id = b*256 + t (guard <= NN; bucket b+1 rewrites its own base)
  int gid = b * 256 + t;
  if (gid <= NN) rowptr[gid] = e0 + pref[t];
  // counting-sort scatter into LDS (spill path for oversized buckets)
  for (int i = t; i < s; i += 256){
    uint2 p = pairs[e0 + i];
    int bin = p.y & 255;
    int r = atomicAdd(&cnt[bin], 1);
    int pos = pref[bin] + r;
    if (pos < CAP) lsrc[pos] = (int)p.x;
    else           csr[e0 + pos] = (int)p.x;
  }
  __syncthreads();
  int lim = s < CAP ? s : CAP;
  for (int i = t; i < lim; i += 256) csr[e0 + i] = lsrc[i];
}

// ---------------- dtype conversion ----------------

__global__ void f2b_vec_k(const float* __restrict__ in, bf16_t* __restrict__ out, int n){
  int g = blockIdx.x * 256 + threadIdx.x;
  int i = g * 4;
  if (i < n){
    float4 v = *(const float4*)(in + i);
    uint2 u;
    u.x = (u32)f2b(v.x) | ((u32)f2b(v.y) << 16);
    u.y = (u32)f2b(v.z) | ((u32)f2b(v.w) << 16);
    *(uint2*)(out + i) = u;
  }
}

struct WtArgs {
  const float* W[6];
  bf16_t* Wt[6];
  int K[6], N[6];
  int off[7];
};

__global__ void wt_all_k(WtArgs a){
  int g = blockIdx.x * 256 + threadIdx.x;
  if (g >= a.off[6]) return;
  #pragma unroll
  for (int s = 0; s < 6; ++s){
    if (g >= a.off[s] && g < a.off[s + 1]){
      int local = g - a.off[s];
      int K = a.K[s], N = a.N[s];
      int n = local / K, k = local - n * K;
      a.Wt[s][local] = f2b(a.W[s][(size_t)k * N + n]);
    }
  }
}

// ---------------- per-row quantization: one wave per row ----------------

template<int C, bool SIGNED, typename TIN>
__global__ __launch_bounds__(256) void quant_k(const TIN* __restrict__ in,
    uint8_t* __restrict__ outq, float* __restrict__ scales){
  constexpr int V = C / 64;
  int row  = (blockIdx.x * 256 + threadIdx.x) >> 6;
  int lane = threadIdx.x & 63;
  if (row >= NN) return;
  float v[V];
  if constexpr (sizeof(TIN) == 4){
    float2 u = *(const float2*)((const float*)in + (size_t)row * C + lane * 2);
    v[0] = u.x; v[1] = u.y;
  } else {
    const bf16_t* bp = (const bf16_t*)in + (size_t)row * C + lane * V;
    if constexpr (V == 4){
      uint2 u = *(const uint2*)bp;
      v[0] = b2f((unsigned short)(u.x & 0xffffu)); v[1] = b2f((unsigned short)(u.x >> 16));
      v[2] = b2f((unsigned short)(u.y & 0xffffu)); v[3] = b2f((unsigned short)(u.y >> 16));
    } else if constexpr (V == 2){
      u32 u = *(const u32*)bp;
      v[0] = b2f((unsigned short)(u & 0xffffu)); v[1] = b2f((unsigned short)(u >> 16));
    } else {
      v[0] = b2f(*bp);
    }
  }
  float m = 0.f;
  #pragma unroll
  for (int i = 0; i < V; ++i) m = fmaxf(m, SIGNED ? fabsf(v[i]) : v[i]);
  #pragma unroll
  for (int msk = 1; msk < 64; msk <<= 1) m = fmaxf(m, __shfl_xor(m, msk, 64));
  const float qmax = SIGNED ? 127.f : 255.f;
  float inv = m > 0.f ? qmax / m : 0.f;
  uint8_t qb[V];
  #pragma unroll
  for (int i = 0; i < V; ++i){
    float qf = rintf(v[i] * inv);
    if (SIGNED){
      qf = fminf(fmaxf(qf, -127.f), 127.f);
      qb[i] = (uint8_t)(int8_t)(int)qf;
    } else {
      qf = fminf(fmaxf(qf, 0.f), 255.f);
      qb[i] = (uint8_t)(int)qf;
    }
  }
  uint8_t* op = outq + (size_t)row * C + lane * V;
  if constexpr (V == 4){
    u32 p = (u32)qb[0] | ((u32)qb[1] << 8) | ((u32)qb[2] << 16) | ((u32)qb[3] << 24);
    *(u32*)op = p;
  } else if constexpr (V == 2){
    *(unsigned short*)op = (unsigned short)((u32)qb[0] | ((u32)qb[1] << 8));
  } else {
    *op = qb[0];
  }
  if (lane == 0) scales[row] = m / qmax;
}

// ---------------- mean aggregation over quantized rows ----------------

__device__ __forceinline__ float qdec(u32 w, int b, bool sgn){
  u32 byte = (w >> (8 * b)) & 0xffu;
  return sgn ? (float)(int8_t)byte : (float)byte;
}

template<int C, bool SIGNED>
__global__ __launch_bounds__(256) void agg_q8_k(const uint8_t* __restrict__ tq,
    const float* __restrict__ tsc,
    const int* __restrict__ rowptr, const int* __restrict__ csr,
    bf16_t* __restrict__ outm){
  constexpr int V = C / 64;
  int wid  = (blockIdx.x * 256 + threadIdx.x) >> 6;
  int lane = threadIdx.x & 63;
  if (wid >= NN) return;
  int beg = __builtin_amdgcn_readfirstlane(rowptr[wid]);
  int end = __builtin_amdgcn_readfirstlane(rowptr[wid + 1]);
  float acc[V];
  #pragma unroll
  for (int i = 0; i < V; ++i) acc[i] = 0.f;

  const uint8_t* hb = tq + lane * V;
  int e = beg;
  for (; e + 7 < end; e += 8){
    int   s[8]; float sc[8];
    #pragma unroll
    for (int q = 0; q < 8; ++q) s[q] = csr[e + q];
    u32 w[8];
    #pragma unroll
    for (int q = 0; q < 8; ++q){
      if constexpr (V == 4) w[q] = *(const u32*)(hb + (size_t)s[q] * C);
      else                  w[q] = *(const unsigned short*)(hb + (size_t)s[q] * C);
      sc[q] = tsc[s[q]];
    }
    #pragma unroll
    for (int q = 0; q < 8; ++q)
      #pragma unroll
      for (int i = 0; i < V; ++i)
        acc[i] += sc[q] * qdec(w[q], i, SIGNED);
  }
  for (; e < end; ++e){
    int s0 = csr[e];
    u32 w0;
    if constexpr (V == 4) w0 = *(const u32*)(hb + (size_t)s0 * C);
    else                  w0 = *(const unsigned short*)(hb + (size_t)s0 * C);
    float sc0 = tsc[s0];
    #pragma unroll
    for (int i = 0; i < V; ++i) acc[i] += sc0 * qdec(w0, i, SIGNED);
  }

  int d = end - beg;
  float di = d > 0 ? 1.0f / (float)d : 0.f;
  bf16_t* po = outm + (size_t)wid * C + lane * V;
  if constexpr (V == 2){
    u32 u = (u32)f2b(acc[0] * di) | ((u32)f2b(acc[1] * di) << 16);
    *(u32*)po = u;
  } else {
    uint2 u;
    u.x = (u32)f2b(acc[0] * di) | ((u32)f2b(acc[1] * di) << 16);
    u.y = (u32)f2b(acc[2] * di) | ((u32)f2b(acc[3] * di) << 16);
    *(uint2*)po = u;
  }
}

// ---------------- final aggregation (layer 3, C=64, int8 P) ----------------

__global__ __launch_bounds__(256) void agg_final_q8_k(
    const uint8_t* __restrict__ Pq, const float* __restrict__ scp,
    const float* __restrict__ Q,
    const int* __restrict__ rowptr, const int* __restrict__ csr,
    float* __restrict__ out){
  int wid  = (blockIdx.x * 256 + threadIdx.x) >> 6;
  int lane = threadIdx.x & 63;
  if (wid >= NN) return;
  int beg = __builtin_amdgcn_readfirstlane(rowptr[wid]);
  int end = __builtin_amdgcn_readfirstlane(rowptr[wid + 1]);
  const uint8_t* Pb = Pq + lane;
  float acc = 0.f;
  int e = beg;
  for (; e + 7 < end; e += 8){
    int s[8]; uint8_t b[8]; float sc[8];
    #pragma unroll
    for (int q = 0; q < 8; ++q) s[q] = csr[e + q];
    #pragma unroll
    for (int q = 0; q < 8; ++q){ b[q] = Pb[(size_t)s[q] * 64]; sc[q] = scp[s[q]]; }
    #pragma unroll
    for (int q = 0; q < 8; ++q) acc += sc[q] * (float)(int8_t)b[q];
  }
  for (; e < end; ++e) acc += scp[csr[e]] * (float)(int8_t)Pb[(size_t)csr[e] * 64];
  int d = end - beg;
  float di = d > 0 ? 1.0f / (float)d : 0.f;
  out[(size_t)wid * 64 + lane] = acc * di + Q[(size_t)wid * 64 + lane];
}

// ---------------- MFMA dual-GEMM + bias + BN + ReLU (layers 1,2) ----------------

template<int BN, int NT_N>
__global__ __launch_bounds__(256) void mfma_gemm_k(
    const bf16_t* __restrict__ A0, const bf16_t* __restrict__ A1,
    const bf16_t* __restrict__ W0t, const bf16_t* __restrict__ W1t,
    const float* __restrict__ bias,
    const float* __restrict__ gamma, const float* __restrict__ beta,
    const float* __restrict__ rmean, const float* __restrict__ rvar,
    bf16_t* __restrict__ out, int M, int K, int Nout)
{
  constexpr int BM = 128;
  constexpr int BK = 64;
  constexpr int LDA = BK + 8;
  __shared__ bf16_t As[BM * LDA];
  __shared__ bf16_t Bs[BN * LDA];

  int t    = threadIdx.x;
  int lane = t & 63;
  int wid  = t >> 6;
  int wr   = wid >> 1, wc = wid & 1;
  int l15  = lane & 15;
  int quad = lane >> 4;

  int m0 = blockIdx.x * BM;
  int n0 = blockIdx.y * BN;

  f32x4 acc[4][NT_N];
  #pragma unroll
  for (int i = 0; i < 4; ++i)
    #pragma unroll
    for (int j = 0; j < NT_N; ++j)
      acc[i][j] = (f32x4){0.f, 0.f, 0.f, 0.f};

  for (int pass = 0; pass < 2; ++pass){
    const bf16_t* A  = pass ? A1 : A0;
    const bf16_t* Wt = pass ? W1t : W0t;
    for (int k0 = 0; k0 < K; k0 += BK){
      #pragma unroll
      for (int i = 0; i < (BM * (BK/8)) / 256; ++i){
        int c = t + i * 256;
        int row = c >> 3, k8 = c & 7;
        uint4 v = make_uint4(0u, 0u, 0u, 0u);
        int gm = m0 + row;
        if (gm < M) v = *(const uint4*)(A + (size_t)gm * K + k0 + k8 * 8);
        *(uint4*)(As + row * LDA + k8 * 8) = v;
      }
      #pragma unroll
      for (int i = 0; i < (BN * (BK/8)) / 256; ++i){
        int c = t + i * 256;
        int row = c >> 3, k8 = c & 7;
        uint4 v = *(const uint4*)(Wt + (size_t)(n0 + row) * K + k0 + k8 * 8);
        *(uint4*)(Bs + row * LDA + k8 * 8) = v;
      }
      __syncthreads();
      #pragma unroll
      for (int kk = 0; kk < BK; kk += 32){
        bf16x8 af[4], bfr[NT_N];
        #pragma unroll
        for (int i = 0; i < 4; ++i)
          af[i] = *(const bf16x8*)(As + (wr * 64 + i * 16 + l15) * LDA + kk + quad * 8);
        #pragma unroll
        for (int j = 0; j < NT_N; ++j)
          bfr[j] = *(const bf16x8*)(Bs + (wc * (NT_N * 16) + j * 16 + l15) * LDA + kk + quad * 8);
        #pragma unroll
        for (int i = 0; i < 4; ++i)
          #pragma unroll
          for (int j = 0; j < NT_N; ++j)
            acc[i][j] = __builtin_amdgcn_mfma_f32_16x16x32_bf16(af[i], bfr[j], acc[i][j], 0, 0, 0);
      }
      __syncthreads();
    }
  }

  #pragma unroll
  for (int j = 0; j < NT_N; ++j){
    int col = n0 + wc * (NT_N * 16) + j * 16 + l15;
    float sc = gamma[col] * rsqrtf(rvar[col] + 1e-5f);
    float shift = (bias[col] - rmean[col]) * sc + beta[col];
    #pragma unroll
    for (int i = 0; i < 4; ++i){
      int rbase = m0 + wr * 64 + i * 16 + quad * 4;
      #pragma unroll
      for (int r = 0; r < 4; ++r){
        int row = rbase + r;
        if (row < M){
          float v = fmaxf(acc[i][j][r] * sc + shift, 0.f);
          out[(size_t)row * Nout + col] = f2b(v);
        }
      }
    }
  }
}

// ---------------- layer-3 single-A GEMM: P = A@Wcl (bf16), Q = A@Wcr + bcl (f32) ----------------

__global__ __launch_bounds__(256) void gemm3_k(
    const bf16_t* __restrict__ A, const bf16_t* __restrict__ Wt,
    const float* __restrict__ bcl,
    bf16_t* __restrict__ P, float* __restrict__ Q, int M)
{
  constexpr int BM = 128, BN = 128, BK = 64, K = 256;
  constexpr int LDA = BK + 8;
  __shared__ bf16_t As[BM * LDA];
  __shared__ bf16_t Bs[BN * LDA];

  int t    = threadIdx.x;
  int lane = t & 63;
  int wid  = t >> 6;
  int wr   = wid >> 1, wc = wid & 1;
  int l15  = lane & 15;
  int quad = lane >> 4;
  int m0 = blockIdx.x * BM;

  f32x4 acc[4][4];
  #pragma unroll
  for (int i = 0; i < 4; ++i)
    #pragma unroll
    for (int j = 0; j < 4; ++j)
      acc[i][j] = (f32x4){0.f, 0.f, 0.f, 0.f};

  for (int k0 = 0; k0 < K; k0 += BK){
    #pragma unroll
    for (int i = 0; i < 4; ++i){
      int c = t + i * 256;
      int row = c >> 3, k8 = c & 7;
      uint4 v = make_uint4(0u, 0u, 0u, 0u);
      int gm = m0 + row;
      if (gm < M) v = *(const uint4*)(A + (size_t)gm * K + k0 + k8 * 8);
      *(uint4*)(As + row * LDA + k8 * 8) = v;
    }
    #pragma unroll
    for (int i = 0; i < 4; ++i){
      int c = t + i * 256;
      int row = c >> 3, k8 = c & 7;
      uint4 v = *(const uint4*)(Wt + (size_t)row * K + k0 + k8 * 8);
      *(uint4*)(Bs + row * LDA + k8 * 8) = v;
    }
    __syncthreads();
    #pragma unroll
    for (int kk = 0; kk < BK; kk += 32){
      bf16x8 af[4], bfr[4];
      #pragma unroll
      for (int i = 0; i < 4; ++i)
        af[i] = *(const bf16x8*)(As + (wr * 64 + i * 16 + l15) * LDA + kk + quad * 8);
      #pragma unroll
      for (int j = 0; j < 4; ++j)
        bfr[j] = *(const bf16x8*)(Bs + (wc * 64 + j * 16 + l15) * LDA + kk + quad * 8);
      #pragma unroll
      for (int i = 0; i < 4; ++i)
        #pragma unroll
        for (int j = 0; j < 4; ++j)
          acc[i][j] = __builtin_amdgcn_mfma_f32_16x16x32_bf16(af[i], bfr[j], acc[i][j], 0, 0, 0);
    }
    __syncthreads();
  }

  #pragma unroll
  for (int j = 0; j < 4; ++j){
    int col = wc * 64 + j * 16 + l15;      // 0..127
    #pragma unroll
    for (int i = 0; i < 4; ++i){
      int rbase = m0 + wr * 64 + i * 16 + quad * 4;
      #pragma unroll
      for (int r = 0; r < 4; ++r){
        int row = rbase + r;
        if (row < M){
          float v = acc[i][j][r];
          if (col < 64) P[(size_t)row * 64 + col] = f2b(v);
          else          Q[(size_t)row * 64 + (col - 64)] = v + bcl[col - 64];
        }
      }
    }
  }
}

// ---------------- launch ----------------

extern "C" void kernel_launch(void* const* d_in, const int* in_sizes, int n_in,
                              void* d_out, int out_size, void* d_ws, size_t ws_size,
                              hipStream_t stream)
{
  const float* x   = (const float*)d_in[0];
  const int*   ei  = (const int*)d_in[1];
  const float* W1l = (const float*)d_in[2];
  const float* b1l = (const float*)d_in[3];
  const float* W1r = (const float*)d_in[4];
  const float* g1  = (const float*)d_in[5];
  const float* be1 = (const float*)d_in[6];
  const float* rm1 = (const float*)d_in[7];
  const float* rv1 = (const float*)d_in[8];
  const float* W2l = (const float*)d_in[9];
  const float* b2l = (const float*)d_in[10];
  const float* W2r = (const float*)d_in[11];
  const float* g2  = (const float*)d_in[12];
  const float* be2 = (const float*)d_in[13];
  const float* rm2 = (const float*)d_in[14];
  const float* rv2 = (const float*)d_in[15];
  const float* Wcl = (const float*)d_in[16];
  const float* bcl = (const float*)d_in[17];
  const float* Wcr = (const float*)d_in[18];
  (void)in_sizes; (void)n_in; (void)out_size; (void)ws_size;

  char* ws = (char*)d_ws;
  size_t off = 0;
  auto alloc = [&](size_t bytes)->char* {
    char* p = ws + off;
    off += (bytes + 15) & ~(size_t)15;
    return p;
  };
  int*    bcnt   = (int*)   alloc(800 * 4);             // [NB] counts + [NB] fill (contig)
  int*    bfill  = bcnt + 400;
  int*    bbase  = (int*)   alloc((size_t)(NB + 1) * 4);
  int*    rowptr = (int*)   alloc((size_t)(NN + 1) * 4);
  int*    eflag  = (int*)   alloc(16);
  int*    csr    = (int*)   alloc((size_t)EE * 4);
  bf16_t* xb     = (bf16_t*)alloc((size_t)NN * IN_C * 2);
  bf16_t* aggb   = (bf16_t*)alloc((size_t)NN * HID_C * 2);
  bf16_t* h1     = (bf16_t*)alloc((size_t)NN * HID_C * 2);
  bf16_t* h2     = (bf16_t*)alloc((size_t)NN * HID_C * 2);
  bf16_t* W1lt   = (bf16_t*)alloc((size_t)IN_C  * HID_C * 2);
  bf16_t* W1rt   = (bf16_t*)alloc((size_t)IN_C  * HID_C * 2);
  bf16_t* W2lt   = (bf16_t*)alloc((size_t)HID_C * HID_C * 2);
  bf16_t* W2rt   = (bf16_t*)alloc((size_t)HID_C * HID_C * 2);
  bf16_t* Wc3t   = (bf16_t*)alloc((size_t)128 * HID_C * 2);  // [128][256] concat
  float*  sc1    = (float*) alloc((size_t)NN * 4);           // h1 row scales
  float*  scp    = (float*) alloc((size_t)NN * 4);           // P row scales

  // aliases into dead-by-then regions:
  uint2*   pairs = (uint2*)aggb;                     // [E] (src,dst), CSR build only
  uint8_t* xq  = (uint8_t*)h2;                       // [N,128] s8, dead before GEMM2 writes h2
  float*   scx = (float*)((char*)h2 + (size_t)NN * IN_C);
  uint8_t* h1q = (uint8_t*)xb;                       // [N,256] u8, xb dead after GEMM1
  bf16_t*  P   = xb;                                 // [N,64] bf16, h1q dead after layer-2 agg
  uint8_t* Pq  = (uint8_t*)aggb;                     // [N,64] s8, aggb dead after GEMM2
  float*   Q   = (float*)h1;                         // [N,64] f32, h1 dead after GEMM2

  hipMemsetAsync(bcnt, 0, 800 * 4, stream);

  // conversions
  f2b_vec_k<<<(NN * IN_C / 4 + 255) / 256, 256, 0, stream>>>(x, xb, NN * IN_C);
  WtArgs wa;
  wa.W[0] = W1l; wa.Wt[0] = W1lt; wa.K[0] = IN_C;  wa.N[0] = HID_C;
  wa.W[1] = W1r; wa.Wt[1] = W1rt; wa.K[1] = IN_C;  wa.N[1] = HID_C;
  wa.W[2] = W2l; wa.Wt[2] = W2lt; wa.K[2] = HID_C; wa.N[2] = HID_C;
  wa.W[3] = W2r; wa.Wt[3] = W2rt; wa.K[3] = HID_C; wa.N[3] = HID_C;
  wa.W[4] = Wcl; wa.Wt[4] = Wc3t;             wa.K[4] = HID_C; wa.N[4] = OUT_C;
  wa.W[5] = Wcr; wa.Wt[5] = Wc3t + 64 * 256;  wa.K[5] = HID_C; wa.N[5] = OUT_C;
  wa.off[0] = 0;
  for (int s = 0; s < 6; ++s) wa.off[s + 1] = wa.off[s] + wa.K[s] * wa.N[s];
  wt_all_k<<<(wa.off[6] + 255) / 256, 256, 0, stream>>>(wa);

  // CSR build (bucketed two-phase sort)
  detect_edge_k<<<1, 256, 0, stream>>>(ei, eflag);
  bcount_k<<<K3_BLOCKS, 256, 0, stream>>>(ei, eflag, bcnt);
  bscan_k<<<1, 512, 0, stream>>>(bcnt, bbase);
  bscatter_k<<<K3_BLOCKS, 256, 0, stream>>>(ei, eflag, bbase, bfill, pairs);
  bsort_k<<<NB, 256, 0, stream>>>(pairs, bbase, rowptr, csr);

  int wb = (NN + 3) / 4;        // one wave per row/node kernels
  int mblocks = (NN + 127) / 128;

  // layer 1: quantize x (s8 per-row), agg, dual GEMM -> h1 (BN+ReLU)
  quant_k<IN_C, true, float><<<wb, 256, 0, stream>>>(x, xq, scx);
  agg_q8_k<IN_C, true><<<wb, 256, 0, stream>>>(xq, scx, rowptr, csr, aggb);
  dim3 g1d(mblocks, HID_C / 128);
  mfma_gemm_k<128, 4><<<g1d, 256, 0, stream>>>(
      aggb, xb, W1lt, W1rt, b1l, g1, be1, rm1, rv1, h1, NN, IN_C, HID_C);

  // layer 2: quantize h1 (u8 per-row, post-ReLU), agg, dual GEMM -> h2 (BN+ReLU)
  quant_k<HID_C, false, bf16_t><<<wb, 256, 0, stream>>>(h1, h1q, sc1);
  agg_q8_k<HID_C, false><<<wb, 256, 0, stream>>>(h1q, sc1, rowptr, csr, aggb);
  mfma_gemm_k<128, 4><<<g1d, 256, 0, stream>>>(
      aggb, h1, W2lt, W2rt, b2l, g2, be2, rm2, rv2, h2, NN, HID_C, HID_C);

  // layer 3 (linearity-reordered): P = h2@Wcl, Q = h2@Wcr + bcl; out = agg(P) + Q
  gemm3_k<<<mblocks, 256, 0, stream>>>(h2, Wc3t, bcl, P, Q, NN);
  quant_k<OUT_C, true, bf16_t><<<wb, 256, 0, stream>>>(P, Pq, scp);
  agg_final_q8_k<<<wb, 256, 0, stream>>>(Pq, scp, Q, rowptr, csr, (float*)d_out);
}